// Round 7
// baseline (283.921 us; speedup 1.0000x reference)
//
#include <hip/hip_runtime.h>

#define NN 100000
#define IC 128
#define OC 64
#define NE 1000000

#define NBUCK 64
#define BN 1568         // nodes per bucket; 64*1568 = 100352 >= NN
#define RCAP 18432      // bucket region capacity (mean 15625, +22 sigma)
#define EPB 2048        // edges per binning block
#define CAPA 64         // LDS buffer entries per bucket in k_binA
#define GPAD 16         // gcur padding: one counter per 64B line
#define LDW 136         // epilogue LDS row stride (128 + 8 pad), ushorts

typedef __attribute__((ext_vector_type(8))) short short8;
typedef __attribute__((ext_vector_type(4))) float f32x4;

static __device__ __forceinline__ float b2f(unsigned short u) {
    unsigned v = ((unsigned)u) << 16;
    float f;
    __builtin_memcpy(&f, &v, 4);
    return f;
}
static __device__ __forceinline__ unsigned short f2b(float f) {
    unsigned u;
    __builtin_memcpy(&u, &f, 4);
    u += 0x7fff + ((u >> 16) & 1);
    return (unsigned short)(u >> 16);
}

// ---------------- CSR pass A: partition edges into 64 dst-range buckets ----------------
__global__ __launch_bounds__(256) void k_binA(const int* __restrict__ src,
                                              const int* __restrict__ dst,
                                              int* __restrict__ gcur,
                                              unsigned* __restrict__ bins) {
    __shared__ unsigned buf[NBUCK][CAPA];
    __shared__ int lcnt[NBUCK];
    const int t = threadIdx.x;
    if (t < NBUCK) lcnt[t] = 0;
    __syncthreads();
    const int e0 = blockIdx.x * EPB;
#pragma unroll
    for (int q = 0; q < EPB / 256; ++q) {
        int e = e0 + q * 256 + t;
        if (e < NE) {
            int d = dst[e];
            int s = src[e];
            int b = d / BN;
            unsigned packed = ((unsigned)(d - b * BN) << 17) | (unsigned)s;
            int idx = atomicAdd(&lcnt[b], 1);
            if (idx < CAPA) {
                buf[b][idx] = packed;
            } else {
                int g = atomicAdd(&gcur[b * GPAD], 1);
                if (g < RCAP) bins[(size_t)b * RCAP + g] = packed;
            }
        }
    }
    __syncthreads();
    const int wid = t >> 6, lane = t & 63;
    for (int b = wid * 16; b < wid * 16 + 16; ++b) {
        int c = lcnt[b];
        if (c > CAPA) c = CAPA;
        if (c > 0) {
            int g = 0;
            if (lane == 0) g = atomicAdd(&gcur[b * GPAD], c);
            g = __shfl(g, 0, 64);
            if (lane < c && g + lane < RCAP)
                bins[(size_t)b * RCAP + g + lane] = buf[b][lane];
        }
    }
}

// ---------------- CSR: exclusive scan of 64 bucket counts (one wave) ----------------
__global__ __launch_bounds__(64) void k_bscan(const int* __restrict__ gcur,
                                              int* __restrict__ bstart,
                                              int* __restrict__ row_ptr) {
    const int t = threadIdx.x;
    int v = gcur[t * GPAD];
    if (v > RCAP) v = RCAP;
    int s = v;
    for (int off = 1; off < 64; off <<= 1) {
        int u = __shfl_up(s, off, 64);
        if (t >= off) s += u;
    }
    bstart[t] = s - v;
    if (t == 63) row_ptr[NN] = s;
}

// ---------------- CSR pass B: per-bucket hist + scan + place (all coalesced) ----------------
__global__ __launch_bounds__(512) void k_binB(const int* __restrict__ gcur,
                                              const int* __restrict__ bstart,
                                              const unsigned* __restrict__ bins,
                                              int* __restrict__ row_ptr,
                                              int* __restrict__ csr) {
    __shared__ int lc[2048];
    __shared__ int rk[2048];
    __shared__ int tsum[512];
    __shared__ int seg[RCAP];
    const int b = blockIdx.x;
    const int t = threadIdx.x;
    const int base = b * BN;
    const int nloc = (NN - base < BN) ? (NN - base) : BN;
    for (int i = t; i < 2048; i += 512) { lc[i] = 0; rk[i] = 0; }
    __syncthreads();
    int c = gcur[b * GPAD];
    if (c > RCAP) c = RCAP;
    const unsigned* mb = bins + (size_t)b * RCAP;
    for (int i = t; i < c; i += 512) atomicAdd(&lc[mb[i] >> 17], 1);
    __syncthreads();
    int loc[4], s = 0;
#pragma unroll
    for (int q = 0; q < 4; ++q) { loc[q] = lc[t * 4 + q]; s += loc[q]; }
    tsum[t] = s;
    __syncthreads();
    for (int off = 1; off < 512; off <<= 1) {
        int u = (t >= off) ? tsum[t - off] : 0;
        __syncthreads();
        tsum[t] += u;
        __syncthreads();
    }
    int run = tsum[t] - s;
#pragma unroll
    for (int q = 0; q < 4; ++q) { lc[t * 4 + q] = run; run += loc[q]; }
    __syncthreads();
    const int bs = bstart[b];
    for (int i = t; i < nloc; i += 512) row_ptr[base + i] = bs + lc[i];
    for (int i = t; i < c; i += 512) {
        unsigned p = mb[i];
        int dl = p >> 17;
        int r = atomicAdd(&rk[dl], 1);
        seg[lc[dl] + r] = (int)(p & 0x1FFFFu);
    }
    __syncthreads();
    for (int i = t; i < c; i += 512) csr[bs + i] = seg[i];
}

// ---------------- x fp32 -> bf16 ----------------
__global__ __launch_bounds__(256) void k_cvt(const float* __restrict__ x,
                                             unsigned short* __restrict__ xb) {
    int t = blockIdx.x * 256 + threadIdx.x;
    if (t >= NN * IC / 8) return;
    const float4* p = (const float4*)x + (size_t)t * 2;
    float4 f0 = p[0], f1 = p[1];
    short8 o;
    o[0] = (short)f2b(f0.x); o[1] = (short)f2b(f0.y);
    o[2] = (short)f2b(f0.z); o[3] = (short)f2b(f0.w);
    o[4] = (short)f2b(f1.x); o[5] = (short)f2b(f1.y);
    o[6] = (short)f2b(f1.z); o[7] = (short)f2b(f1.w);
    *((short8*)xb + t) = o;
}

// ---------------- weight prep ----------------
__global__ __launch_bounds__(256) void k_wprep(
    const float* __restrict__ W1l, const float* __restrict__ W1r,
    const float* __restrict__ Wml, const float* __restrict__ Wmr,
    const float* __restrict__ Wsl, const float* __restrict__ Wsr,
    unsigned short* __restrict__ Wt1, unsigned short* __restrict__ Wt2) {
    int t = blockIdx.x * 256 + threadIdx.x;
    if (t >= 2 * 128 * 256) return;
    int layer = t >> 15;
    int rem = t & 32767;
    int col = rem >> 8;
    int k = rem & 255;
    float v;
    if (layer == 0) {
        v = (k < 128) ? W1l[k * 128 + col] : W1r[(k - 128) * 128 + col];
        Wt1[col * 256 + k] = f2b(v);
    } else {
        if (col < OC) v = (k < 128) ? Wml[k * OC + col] : Wmr[(k - 128) * OC + col];
        else {
            int c2 = col - OC;
            v = (k < 128) ? Wsl[k * OC + c2] : Wsr[(k - 128) * OC + c2];
        }
        Wt2[col * 256 + k] = f2b(v);
    }
}

// ---------------- gather mean-aggregation: one 16-lane slot per node, 8-deep unroll ----------------
__global__ __launch_bounds__(256) void k_agg(const unsigned short* __restrict__ feat,
                                             const int* __restrict__ row_ptr,
                                             const int* __restrict__ csr,
                                             unsigned short* __restrict__ agg) {
    const int lane = threadIdx.x & 63;
    const int wid = threadIdx.x >> 6;
    const int slot = lane >> 4;
    const int cg = lane & 15;
    const int node = blockIdx.x * 16 + wid * 4 + slot;
    if (node >= NN) return;
    const int beg = row_ptr[node];
    const int end = row_ptr[node + 1];
    float acc[8];
#pragma unroll
    for (int q = 0; q < 8; ++q) acc[q] = 0.f;

    for (int j = beg; j < end; j += 8) {
        const int nl = end - j;
        short8 v[8];
#pragma unroll
        for (int u = 0; u < 8; ++u) {
            if (u < nl) {
                int s = csr[j + u];
                v[u] = *(const short8*)(feat + (size_t)s * IC + cg * 8);
            }
        }
#pragma unroll
        for (int u = 0; u < 8; ++u) {
            if (u < nl) {
#pragma unroll
                for (int q = 0; q < 8; ++q) acc[q] += b2f((unsigned short)v[u][q]);
            }
        }
    }
    float inv = 1.0f / fmaxf((float)(end - beg), 1.0f);
    short8 o;
#pragma unroll
    for (int q = 0; q < 8; ++q) o[q] = (short)f2b(acc[q] * inv);
    *(short8*)(agg + (size_t)node * IC + cg * 8) = o;
}

// ---------------- MFMA SAGE GEMM: out = [Agg | X] @ Wt + b ----------------
// 16 rows per wave, 64 rows per block; grid = 1563 blocks (2x waves vs prev round).
// MODE 0: bias+relu -> LDS-staged coalesced bf16 stores (h, stride 128)
// MODE 1: bias -> direct fp32 stores (mu cols 0-63, logstd cols 64-127)
template <int MODE>
__global__ __launch_bounds__(256) void k_gemm(
    const unsigned short* __restrict__ Agg, const unsigned short* __restrict__ Xb,
    const unsigned short* __restrict__ Wt,
    const float* __restrict__ bias0, const float* __restrict__ bias1,
    unsigned short* __restrict__ hout, float* __restrict__ out_mu,
    float* __restrict__ out_ls) {
    const int lane = threadIdx.x & 63;
    const int wid = threadIdx.x >> 6;
    const int rowg = blockIdx.x * 64 + wid * 16;  // wave's 16-row tile
    const int r16 = lane & 15;
    const int k8 = (lane >> 4) * 8;

    __shared__ unsigned short sstage[MODE == 0 ? 4 * 16 * LDW : 4];

    f32x4 acc[8];
#pragma unroll
    for (int nt = 0; nt < 8; ++nt) acc[nt] = (f32x4){0.f, 0.f, 0.f, 0.f};

    int r = rowg + r16;
    const int rA = (r < NN) ? r : (NN - 1);

#pragma unroll
    for (int ks = 0; ks < 8; ++ks) {
        const int kbase = ks * 32;
        const unsigned short* Ah = (kbase < 128) ? Agg : Xb;
        const int koff = (kbase & 127) + k8;
        short8 aF = *(const short8*)(Ah + (size_t)rA * IC + koff);
#pragma unroll
        for (int nt = 0; nt < 8; ++nt) {
            short8 bF = *(const short8*)(Wt + (nt * 16 + r16) * 256 + kbase + k8);
            acc[nt] = __builtin_amdgcn_mfma_f32_16x16x32_bf16(aF, bF, acc[nt], 0, 0, 0);
        }
    }

    const int rbase = (lane >> 4) * 4;
    if (MODE == 0) {
        unsigned short* ws = &sstage[wid * 16 * LDW];
#pragma unroll
        for (int nt = 0; nt < 8; ++nt) {
            const int c = nt * 16 + r16;
            const float bv = bias0[c];
#pragma unroll
            for (int q = 0; q < 4; ++q) {
                float v = fmaxf(acc[nt][q] + bv, 0.f);
                ws[(rbase + q) * LDW + c] = f2b(v);
            }
        }
        __syncthreads();
#pragma unroll
        for (int p = 0; p < 4; ++p) {
            const int rloc = p * 4 + (lane >> 4);
            const int row = rowg + rloc;
            if (row < NN) {
                short8 v = *(const short8*)&ws[rloc * LDW + r16 * 8];
                *(short8*)(hout + (size_t)row * IC + r16 * 8) = v;
            }
        }
    } else {
#pragma unroll
        for (int nt = 0; nt < 8; ++nt) {
            const int c = nt * 16 + r16;
            const float bv = (c < OC) ? bias0[c] : bias1[c - OC];
#pragma unroll
            for (int q = 0; q < 4; ++q) {
                const int row = rowg + rbase + q;
                if (row >= NN) continue;
                float v = acc[nt][q] + bv;
                if (c < OC) out_mu[(size_t)row * OC + c] = v;
                else        out_ls[(size_t)row * OC + (c - OC)] = v;
            }
        }
    }
}

extern "C" void kernel_launch(void* const* d_in, const int* in_sizes, int n_in,
                              void* d_out, int out_size, void* d_ws, size_t ws_size,
                              hipStream_t stream) {
    const float* x   = (const float*)d_in[0];
    const int*   ei  = (const int*)d_in[1];
    const float* W1l = (const float*)d_in[2];
    const float* W1r = (const float*)d_in[3];
    const float* b1  = (const float*)d_in[4];
    const float* Wml = (const float*)d_in[5];
    const float* Wmr = (const float*)d_in[6];
    const float* bm  = (const float*)d_in[7];
    const float* Wsl = (const float*)d_in[8];
    const float* Wsr = (const float*)d_in[9];
    const float* bs  = (const float*)d_in[10];

    const int* src = ei;
    const int* dst = ei + NE;

    // workspace layout (bytes)
    char* w = (char*)d_ws;
    unsigned short* xb   = (unsigned short*)(w);                 // 25,600,000
    unsigned short* hb   = (unsigned short*)(w + 25600000);      // 25,600,000
    unsigned short* aggb = (unsigned short*)(w + 51200000);      // 25,600,000
    unsigned short* Wt1  = (unsigned short*)(w + 76800000);      // 65,536
    unsigned short* Wt2  = (unsigned short*)(w + 76865536);      // 65,536
    int* row_ptr  = (int*)(w + 76931072);                        // 400,064 (padded)
    int* csr      = (int*)(w + 77331136);                        // 4,000,000
    int* gcur     = (int*)(w + 81331136);                        // 4,096
    int* bstart   = (int*)(w + 81335232);                        // 1,024
    unsigned* bins = (unsigned*)(w + 81336256);                  // 4,718,592

    float* out_mu = (float*)d_out;
    float* out_ls = out_mu + (size_t)NN * OC;

    const int gemm_grid = (NN + 63) / 64;
    const int agg_grid = (NN + 15) / 16;
    const int binA_grid = (NE + EPB - 1) / EPB;

    // ---- CSR build (shared by both layers) ----
    hipMemsetAsync(gcur, 0, NBUCK * GPAD * sizeof(int), stream);
    k_binA<<<binA_grid, 256, 0, stream>>>(src, dst, gcur, bins);
    k_bscan<<<1, 64, 0, stream>>>(gcur, bstart, row_ptr);
    k_binB<<<NBUCK, 512, 0, stream>>>(gcur, bstart, bins, row_ptr, csr);

    // conversions / weight prep
    k_cvt<<<(NN * IC / 8 + 255) / 256, 256, 0, stream>>>(x, xb);
    k_wprep<<<(2 * 128 * 256 + 255) / 256, 256, 0, stream>>>(W1l, W1r, Wml, Wmr, Wsl, Wsr, Wt1, Wt2);

    // layer 1
    k_agg<<<agg_grid, 256, 0, stream>>>(xb, row_ptr, csr, aggb);
    k_gemm<0><<<gemm_grid, 256, 0, stream>>>(aggb, xb, Wt1, b1, nullptr,
                                             hb, nullptr, nullptr);

    // layer 2 (shared aggregation feeds mu and logstd)
    k_agg<<<agg_grid, 256, 0, stream>>>(hb, row_ptr, csr, aggb);
    k_gemm<1><<<gemm_grid, 256, 0, stream>>>(aggb, hb, Wt2, bm, bs,
                                             nullptr, out_mu, out_ls);
}

// Round 8
// 243.411 us; speedup vs baseline: 1.1664x; 1.1664x over previous
//
#include <hip/hip_runtime.h>

#define NN 100000
#define IC 128
#define OC 64
#define NE 1000000

#define NBUCK 64
#define BN 1568         // nodes per bucket; 64*1568 = 100352 >= NN
#define RCAP 18432      // bucket region capacity (mean 15625, +22 sigma)
#define EPB 2048        // edges per binning block
#define CAPA 64         // LDS buffer entries per bucket in k_binA
#define GPAD 16         // gcur padding: one counter per 64B line
#define LDW 136         // epilogue LDS row stride (128 + 8 pad), ushorts

typedef __attribute__((ext_vector_type(8))) short short8;
typedef __attribute__((ext_vector_type(4))) float f32x4;

static __device__ __forceinline__ float b2f(unsigned short u) {
    unsigned v = ((unsigned)u) << 16;
    float f;
    __builtin_memcpy(&f, &v, 4);
    return f;
}
static __device__ __forceinline__ unsigned short f2b(float f) {
    unsigned u;
    __builtin_memcpy(&u, &f, 4);
    u += 0x7fff + ((u >> 16) & 1);
    return (unsigned short)(u >> 16);
}

// ---------------- CSR pass A: partition edges into 64 dst-range buckets ----------------
__global__ __launch_bounds__(256) void k_binA(const int* __restrict__ src,
                                              const int* __restrict__ dst,
                                              int* __restrict__ gcur,
                                              unsigned* __restrict__ bins) {
    __shared__ unsigned buf[NBUCK][CAPA];
    __shared__ int lcnt[NBUCK];
    const int t = threadIdx.x;
    if (t < NBUCK) lcnt[t] = 0;
    __syncthreads();
    const int e0 = blockIdx.x * EPB;
#pragma unroll
    for (int q = 0; q < EPB / 256; ++q) {
        int e = e0 + q * 256 + t;
        if (e < NE) {
            int d = dst[e];
            int s = src[e];
            int b = d / BN;
            unsigned packed = ((unsigned)(d - b * BN) << 17) | (unsigned)s;
            int idx = atomicAdd(&lcnt[b], 1);
            if (idx < CAPA) {
                buf[b][idx] = packed;
            } else {
                int g = atomicAdd(&gcur[b * GPAD], 1);
                if (g < RCAP) bins[(size_t)b * RCAP + g] = packed;
            }
        }
    }
    __syncthreads();
    const int wid = t >> 6, lane = t & 63;
    for (int b = wid * 16; b < wid * 16 + 16; ++b) {
        int c = lcnt[b];
        if (c > CAPA) c = CAPA;
        if (c > 0) {
            int g = 0;
            if (lane == 0) g = atomicAdd(&gcur[b * GPAD], c);
            g = __shfl(g, 0, 64);
            if (lane < c && g + lane < RCAP)
                bins[(size_t)b * RCAP + g + lane] = buf[b][lane];
        }
    }
}

// ---------------- CSR: exclusive scan of 64 bucket counts (one wave) ----------------
__global__ __launch_bounds__(64) void k_bscan(const int* __restrict__ gcur,
                                              int* __restrict__ bstart,
                                              int* __restrict__ row_ptr) {
    const int t = threadIdx.x;
    int v = gcur[t * GPAD];
    if (v > RCAP) v = RCAP;
    int s = v;
    for (int off = 1; off < 64; off <<= 1) {
        int u = __shfl_up(s, off, 64);
        if (t >= off) s += u;
    }
    bstart[t] = s - v;
    if (t == 63) row_ptr[NN] = s;
}

// ---------------- CSR pass B: per-bucket hist + scan + place (all coalesced) ----------------
__global__ __launch_bounds__(512) void k_binB(const int* __restrict__ gcur,
                                              const int* __restrict__ bstart,
                                              const unsigned* __restrict__ bins,
                                              int* __restrict__ row_ptr,
                                              int* __restrict__ csr) {
    __shared__ int lc[2048];
    __shared__ int rk[2048];
    __shared__ int tsum[512];
    __shared__ int seg[RCAP];
    const int b = blockIdx.x;
    const int t = threadIdx.x;
    const int base = b * BN;
    const int nloc = (NN - base < BN) ? (NN - base) : BN;
    for (int i = t; i < 2048; i += 512) { lc[i] = 0; rk[i] = 0; }
    __syncthreads();
    int c = gcur[b * GPAD];
    if (c > RCAP) c = RCAP;
    const unsigned* mb = bins + (size_t)b * RCAP;
    for (int i = t; i < c; i += 512) atomicAdd(&lc[mb[i] >> 17], 1);
    __syncthreads();
    int loc[4], s = 0;
#pragma unroll
    for (int q = 0; q < 4; ++q) { loc[q] = lc[t * 4 + q]; s += loc[q]; }
    tsum[t] = s;
    __syncthreads();
    for (int off = 1; off < 512; off <<= 1) {
        int u = (t >= off) ? tsum[t - off] : 0;
        __syncthreads();
        tsum[t] += u;
        __syncthreads();
    }
    int run = tsum[t] - s;
#pragma unroll
    for (int q = 0; q < 4; ++q) { lc[t * 4 + q] = run; run += loc[q]; }
    __syncthreads();
    const int bs = bstart[b];
    for (int i = t; i < nloc; i += 512) row_ptr[base + i] = bs + lc[i];
    for (int i = t; i < c; i += 512) {
        unsigned p = mb[i];
        int dl = p >> 17;
        int r = atomicAdd(&rk[dl], 1);
        seg[lc[dl] + r] = (int)(p & 0x1FFFFu);
    }
    __syncthreads();
    for (int i = t; i < c; i += 512) csr[bs + i] = seg[i];
}

// ---------------- x fp32 -> bf16 ----------------
__global__ __launch_bounds__(256) void k_cvt(const float* __restrict__ x,
                                             unsigned short* __restrict__ xb) {
    int t = blockIdx.x * 256 + threadIdx.x;
    if (t >= NN * IC / 8) return;
    const float4* p = (const float4*)x + (size_t)t * 2;
    float4 f0 = p[0], f1 = p[1];
    short8 o;
    o[0] = (short)f2b(f0.x); o[1] = (short)f2b(f0.y);
    o[2] = (short)f2b(f0.z); o[3] = (short)f2b(f0.w);
    o[4] = (short)f2b(f1.x); o[5] = (short)f2b(f1.y);
    o[6] = (short)f2b(f1.z); o[7] = (short)f2b(f1.w);
    *((short8*)xb + t) = o;
}

// ---------------- weight prep ----------------
__global__ __launch_bounds__(256) void k_wprep(
    const float* __restrict__ W1l, const float* __restrict__ W1r,
    const float* __restrict__ Wml, const float* __restrict__ Wmr,
    const float* __restrict__ Wsl, const float* __restrict__ Wsr,
    unsigned short* __restrict__ Wt1, unsigned short* __restrict__ Wt2) {
    int t = blockIdx.x * 256 + threadIdx.x;
    if (t >= 2 * 128 * 256) return;
    int layer = t >> 15;
    int rem = t & 32767;
    int col = rem >> 8;
    int k = rem & 255;
    float v;
    if (layer == 0) {
        v = (k < 128) ? W1l[k * 128 + col] : W1r[(k - 128) * 128 + col];
        Wt1[col * 256 + k] = f2b(v);
    } else {
        if (col < OC) v = (k < 128) ? Wml[k * OC + col] : Wmr[(k - 128) * OC + col];
        else {
            int c2 = col - OC;
            v = (k < 128) ? Wsl[k * OC + c2] : Wsr[(k - 128) * OC + c2];
        }
        Wt2[col * 256 + k] = f2b(v);
    }
}

// ---------------- gather mean-aggregation: one 16-lane slot per node, 8-deep unroll ----------------
__global__ __launch_bounds__(256) void k_agg(const unsigned short* __restrict__ feat,
                                             const int* __restrict__ row_ptr,
                                             const int* __restrict__ csr,
                                             unsigned short* __restrict__ agg) {
    const int lane = threadIdx.x & 63;
    const int wid = threadIdx.x >> 6;
    const int slot = lane >> 4;
    const int cg = lane & 15;
    const int node = blockIdx.x * 16 + wid * 4 + slot;
    if (node >= NN) return;
    const int beg = row_ptr[node];
    const int end = row_ptr[node + 1];
    float acc[8];
#pragma unroll
    for (int q = 0; q < 8; ++q) acc[q] = 0.f;

    for (int j = beg; j < end; j += 8) {
        const int nl = end - j;
        short8 v[8];
#pragma unroll
        for (int u = 0; u < 8; ++u) {
            if (u < nl) {
                int s = csr[j + u];
                v[u] = *(const short8*)(feat + (size_t)s * IC + cg * 8);
            }
        }
#pragma unroll
        for (int u = 0; u < 8; ++u) {
            if (u < nl) {
#pragma unroll
                for (int q = 0; q < 8; ++q) acc[q] += b2f((unsigned short)v[u][q]);
            }
        }
    }
    float inv = 1.0f / fmaxf((float)(end - beg), 1.0f);
    short8 o;
#pragma unroll
    for (int q = 0; q < 8; ++q) o[q] = (short)f2b(acc[q] * inv);
    *(short8*)(agg + (size_t)node * IC + cg * 8) = o;
}

// ---------------- MFMA SAGE GEMM: out = [Agg | X] @ Wt + b ----------------
// 32 rows/wave, 128 rows/block. All 16 A-fragment gathers hoisted (vmcnt MLP);
// B-fragments software-pipelined one K-step ahead (L2-hot).
// MODE 0: bias+relu -> LDS-staged coalesced bf16 stores (h, stride 128)
// MODE 1: bias -> direct fp32 stores (mu cols 0-63, logstd cols 64-127)
template <int MODE>
__global__ __launch_bounds__(256) void k_gemm(
    const unsigned short* __restrict__ Agg, const unsigned short* __restrict__ Xb,
    const unsigned short* __restrict__ Wt,
    const float* __restrict__ bias0, const float* __restrict__ bias1,
    unsigned short* __restrict__ hout, float* __restrict__ out_mu,
    float* __restrict__ out_ls) {
    const int lane = threadIdx.x & 63;
    const int wid = threadIdx.x >> 6;
    const int rowg = blockIdx.x * 128 + wid * 32;  // wave's 32-row tile
    const int r16 = lane & 15;
    const int k8 = (lane >> 4) * 8;

    __shared__ unsigned short sstage[MODE == 0 ? 4 * 32 * LDW : 4];

    int rA[2];
#pragma unroll
    for (int m = 0; m < 2; ++m) {
        int r = rowg + m * 16 + r16;
        rA[m] = (r < NN) ? r : (NN - 1);
    }

    // hoist all 16 A-fragment gathers (issued back-to-back on vmcnt queue)
    short8 aF[2][8];
#pragma unroll
    for (int ks = 0; ks < 4; ++ks) {
        aF[0][ks] = *(const short8*)(Agg + (size_t)rA[0] * IC + ks * 32 + k8);
        aF[1][ks] = *(const short8*)(Agg + (size_t)rA[1] * IC + ks * 32 + k8);
    }
#pragma unroll
    for (int ks = 0; ks < 4; ++ks) {
        aF[0][4 + ks] = *(const short8*)(Xb + (size_t)rA[0] * IC + ks * 32 + k8);
        aF[1][4 + ks] = *(const short8*)(Xb + (size_t)rA[1] * IC + ks * 32 + k8);
    }

    f32x4 acc[2][8];
#pragma unroll
    for (int m = 0; m < 2; ++m)
#pragma unroll
        for (int nt = 0; nt < 8; ++nt) acc[m][nt] = (f32x4){0.f, 0.f, 0.f, 0.f};

    // B pipeline: bcur = K-step ks, bnxt prefetched for ks+1
    short8 bcur[8], bnxt[8];
#pragma unroll
    for (int nt = 0; nt < 8; ++nt)
        bcur[nt] = *(const short8*)(Wt + (nt * 16 + r16) * 256 + k8);

#pragma unroll
    for (int ks = 0; ks < 8; ++ks) {
        if (ks < 7) {
#pragma unroll
            for (int nt = 0; nt < 8; ++nt)
                bnxt[nt] = *(const short8*)(Wt + (nt * 16 + r16) * 256 + (ks + 1) * 32 + k8);
        }
#pragma unroll
        for (int nt = 0; nt < 8; ++nt) {
            acc[0][nt] = __builtin_amdgcn_mfma_f32_16x16x32_bf16(aF[0][ks], bcur[nt], acc[0][nt], 0, 0, 0);
            acc[1][nt] = __builtin_amdgcn_mfma_f32_16x16x32_bf16(aF[1][ks], bcur[nt], acc[1][nt], 0, 0, 0);
        }
#pragma unroll
        for (int nt = 0; nt < 8; ++nt) bcur[nt] = bnxt[nt];
    }

    const int rbase = (lane >> 4) * 4;
    if (MODE == 0) {
        unsigned short* ws = &sstage[wid * 32 * LDW];
#pragma unroll
        for (int m = 0; m < 2; ++m) {
#pragma unroll
            for (int nt = 0; nt < 8; ++nt) {
                const int c = nt * 16 + r16;
                const float bv = bias0[c];
#pragma unroll
                for (int q = 0; q < 4; ++q) {
                    float v = fmaxf(acc[m][nt][q] + bv, 0.f);
                    ws[(m * 16 + rbase + q) * LDW + c] = f2b(v);
                }
            }
        }
        __syncthreads();
#pragma unroll
        for (int p = 0; p < 8; ++p) {
            const int rloc = p * 4 + (lane >> 4);
            const int row = rowg + rloc;
            if (row < NN) {
                short8 v = *(const short8*)&ws[rloc * LDW + r16 * 8];
                *(short8*)(hout + (size_t)row * IC + r16 * 8) = v;
            }
        }
    } else {
#pragma unroll
        for (int m = 0; m < 2; ++m) {
#pragma unroll
            for (int nt = 0; nt < 8; ++nt) {
                const int c = nt * 16 + r16;
                const float bv = (c < OC) ? bias0[c] : bias1[c - OC];
#pragma unroll
                for (int q = 0; q < 4; ++q) {
                    const int row = rowg + m * 16 + rbase + q;
                    if (row >= NN) continue;
                    float v = acc[m][nt][q] + bv;
                    if (c < OC) out_mu[(size_t)row * OC + c] = v;
                    else        out_ls[(size_t)row * OC + (c - OC)] = v;
                }
            }
        }
    }
}

extern "C" void kernel_launch(void* const* d_in, const int* in_sizes, int n_in,
                              void* d_out, int out_size, void* d_ws, size_t ws_size,
                              hipStream_t stream) {
    const float* x   = (const float*)d_in[0];
    const int*   ei  = (const int*)d_in[1];
    const float* W1l = (const float*)d_in[2];
    const float* W1r = (const float*)d_in[3];
    const float* b1  = (const float*)d_in[4];
    const float* Wml = (const float*)d_in[5];
    const float* Wmr = (const float*)d_in[6];
    const float* bm  = (const float*)d_in[7];
    const float* Wsl = (const float*)d_in[8];
    const float* Wsr = (const float*)d_in[9];
    const float* bs  = (const float*)d_in[10];

    const int* src = ei;
    const int* dst = ei + NE;

    // workspace layout (bytes)
    char* w = (char*)d_ws;
    unsigned short* xb   = (unsigned short*)(w);                 // 25,600,000
    unsigned short* hb   = (unsigned short*)(w + 25600000);      // 25,600,000
    unsigned short* aggb = (unsigned short*)(w + 51200000);      // 25,600,000
    unsigned short* Wt1  = (unsigned short*)(w + 76800000);      // 65,536
    unsigned short* Wt2  = (unsigned short*)(w + 76865536);      // 65,536
    int* row_ptr  = (int*)(w + 76931072);                        // 400,064 (padded)
    int* csr      = (int*)(w + 77331136);                        // 4,000,000
    int* gcur     = (int*)(w + 81331136);                        // 4,096
    int* bstart   = (int*)(w + 81335232);                        // 1,024
    unsigned* bins = (unsigned*)(w + 81336256);                  // 4,718,592

    float* out_mu = (float*)d_out;
    float* out_ls = out_mu + (size_t)NN * OC;

    const int gemm_grid = (NN + 127) / 128;
    const int agg_grid = (NN + 15) / 16;
    const int binA_grid = (NE + EPB - 1) / EPB;

    // ---- CSR build (shared by both layers) ----
    hipMemsetAsync(gcur, 0, NBUCK * GPAD * sizeof(int), stream);
    k_binA<<<binA_grid, 256, 0, stream>>>(src, dst, gcur, bins);
    k_bscan<<<1, 64, 0, stream>>>(gcur, bstart, row_ptr);
    k_binB<<<NBUCK, 512, 0, stream>>>(gcur, bstart, bins, row_ptr, csr);

    // conversions / weight prep
    k_cvt<<<(NN * IC / 8 + 255) / 256, 256, 0, stream>>>(x, xb);
    k_wprep<<<(2 * 128 * 256 + 255) / 256, 256, 0, stream>>>(W1l, W1r, Wml, Wmr, Wsl, Wsr, Wt1, Wt2);

    // layer 1
    k_agg<<<agg_grid, 256, 0, stream>>>(xb, row_ptr, csr, aggb);
    k_gemm<0><<<gemm_grid, 256, 0, stream>>>(aggb, xb, Wt1, b1, nullptr,
                                             hb, nullptr, nullptr);

    // layer 2 (shared aggregation feeds mu and logstd)
    k_agg<<<agg_grid, 256, 0, stream>>>(hb, row_ptr, csr, aggb);
    k_gemm<1><<<gemm_grid, 256, 0, stream>>>(aggb, hb, Wt2, bm, bs,
                                             nullptr, out_mu, out_ls);
}

// Round 9
// 200.387 us; speedup vs baseline: 1.4169x; 1.2147x over previous
//
#include <hip/hip_runtime.h>

#define NN 100000
#define IC 128
#define OC 64
#define NE 1000000

#define NBUCK 64
#define BN 1568         // nodes per bucket; 64*1568 = 100352 >= NN
#define RCAP 18432      // bucket region capacity (mean 15625, +22 sigma)
#define EPB 2048        // edges per binning block
#define CAPA 64         // LDS buffer entries per bucket in k_binA
#define GPAD 16         // gcur padding: one counter per 64B line
#define LDW 136         // epilogue LDS row stride (128 + 8 pad), ushorts

typedef __attribute__((ext_vector_type(8))) short short8;
typedef __attribute__((ext_vector_type(4))) float f32x4;

static __device__ __forceinline__ float b2f(unsigned short u) {
    unsigned v = ((unsigned)u) << 16;
    float f;
    __builtin_memcpy(&f, &v, 4);
    return f;
}
static __device__ __forceinline__ unsigned short f2b(float f) {
    unsigned u;
    __builtin_memcpy(&u, &f, 4);
    u += 0x7fff + ((u >> 16) & 1);
    return (unsigned short)(u >> 16);
}

// ---------------- CSR pass A: partition edges into 64 dst-range buckets ----------------
__global__ __launch_bounds__(256) void k_binA(const int* __restrict__ src,
                                              const int* __restrict__ dst,
                                              int* __restrict__ gcur,
                                              unsigned* __restrict__ bins) {
    __shared__ unsigned buf[NBUCK][CAPA];
    __shared__ int lcnt[NBUCK];
    const int t = threadIdx.x;
    if (t < NBUCK) lcnt[t] = 0;
    __syncthreads();
    const int e0 = blockIdx.x * EPB;
#pragma unroll
    for (int q = 0; q < EPB / 256; ++q) {
        int e = e0 + q * 256 + t;
        if (e < NE) {
            int d = dst[e];
            int s = src[e];
            int b = d / BN;
            unsigned packed = ((unsigned)(d - b * BN) << 17) | (unsigned)s;
            int idx = atomicAdd(&lcnt[b], 1);
            if (idx < CAPA) {
                buf[b][idx] = packed;
            } else {
                int g = atomicAdd(&gcur[b * GPAD], 1);
                if (g < RCAP) bins[(size_t)b * RCAP + g] = packed;
            }
        }
    }
    __syncthreads();
    const int wid = t >> 6, lane = t & 63;
    for (int b = wid * 16; b < wid * 16 + 16; ++b) {
        int c = lcnt[b];
        if (c > CAPA) c = CAPA;
        if (c > 0) {
            int g = 0;
            if (lane == 0) g = atomicAdd(&gcur[b * GPAD], c);
            g = __shfl(g, 0, 64);
            if (lane < c && g + lane < RCAP)
                bins[(size_t)b * RCAP + g + lane] = buf[b][lane];
        }
    }
}

// ---------------- CSR: exclusive scan of 64 bucket counts (one wave) ----------------
__global__ __launch_bounds__(64) void k_bscan(const int* __restrict__ gcur,
                                              int* __restrict__ bstart,
                                              int* __restrict__ row_ptr) {
    const int t = threadIdx.x;
    int v = gcur[t * GPAD];
    if (v > RCAP) v = RCAP;
    int s = v;
    for (int off = 1; off < 64; off <<= 1) {
        int u = __shfl_up(s, off, 64);
        if (t >= off) s += u;
    }
    bstart[t] = s - v;
    if (t == 63) row_ptr[NN] = s;
}

// ---------------- CSR pass B: per-bucket hist + scan + place (all coalesced) ----------------
__global__ __launch_bounds__(512) void k_binB(const int* __restrict__ gcur,
                                              const int* __restrict__ bstart,
                                              const unsigned* __restrict__ bins,
                                              int* __restrict__ row_ptr,
                                              int* __restrict__ csr) {
    __shared__ int lc[2048];
    __shared__ int rk[2048];
    __shared__ int tsum[512];
    __shared__ int seg[RCAP];
    const int b = blockIdx.x;
    const int t = threadIdx.x;
    const int base = b * BN;
    const int nloc = (NN - base < BN) ? (NN - base) : BN;
    for (int i = t; i < 2048; i += 512) { lc[i] = 0; rk[i] = 0; }
    __syncthreads();
    int c = gcur[b * GPAD];
    if (c > RCAP) c = RCAP;
    const unsigned* mb = bins + (size_t)b * RCAP;
    for (int i = t; i < c; i += 512) atomicAdd(&lc[mb[i] >> 17], 1);
    __syncthreads();
    int loc[4], s = 0;
#pragma unroll
    for (int q = 0; q < 4; ++q) { loc[q] = lc[t * 4 + q]; s += loc[q]; }
    tsum[t] = s;
    __syncthreads();
    for (int off = 1; off < 512; off <<= 1) {
        int u = (t >= off) ? tsum[t - off] : 0;
        __syncthreads();
        tsum[t] += u;
        __syncthreads();
    }
    int run = tsum[t] - s;
#pragma unroll
    for (int q = 0; q < 4; ++q) { lc[t * 4 + q] = run; run += loc[q]; }
    __syncthreads();
    const int bs = bstart[b];
    for (int i = t; i < nloc; i += 512) row_ptr[base + i] = bs + lc[i];
    for (int i = t; i < c; i += 512) {
        unsigned p = mb[i];
        int dl = p >> 17;
        int r = atomicAdd(&rk[dl], 1);
        seg[lc[dl] + r] = (int)(p & 0x1FFFFu);
    }
    __syncthreads();
    for (int i = t; i < c; i += 512) csr[bs + i] = seg[i];
}

// ---------------- x fp32 -> bf16 ----------------
__global__ __launch_bounds__(256) void k_cvt(const float* __restrict__ x,
                                             unsigned short* __restrict__ xb) {
    int t = blockIdx.x * 256 + threadIdx.x;
    if (t >= NN * IC / 8) return;
    const float4* p = (const float4*)x + (size_t)t * 2;
    float4 f0 = p[0], f1 = p[1];
    short8 o;
    o[0] = (short)f2b(f0.x); o[1] = (short)f2b(f0.y);
    o[2] = (short)f2b(f0.z); o[3] = (short)f2b(f0.w);
    o[4] = (short)f2b(f1.x); o[5] = (short)f2b(f1.y);
    o[6] = (short)f2b(f1.z); o[7] = (short)f2b(f1.w);
    *((short8*)xb + t) = o;
}

// ---------------- weight prep: MFMA-fragment-ordered bf16 weights ----------------
// frag f = (ks*8 + nt)*64 + lane ; element e:
//   k = ks*32 + (lane>>4)*8 + e , col = nt*16 + (lane&15)
// Wf[f*8+e] = Wstack[k][col]  (Wstack = [Wl; Wr], K=256)
__global__ __launch_bounds__(256) void k_wprep(
    const float* __restrict__ W1l, const float* __restrict__ W1r,
    const float* __restrict__ Wml, const float* __restrict__ Wmr,
    const float* __restrict__ Wsl, const float* __restrict__ Wsr,
    unsigned short* __restrict__ Wf1, unsigned short* __restrict__ Wf2) {
    int t = blockIdx.x * 256 + threadIdx.x;
    if (t >= 2 * 4096) return;
    const int layer = t >> 12;
    const int f = t & 4095;
    const int lane = f & 63;
    const int nt = (f >> 6) & 7;
    const int ks = f >> 9;
    const int col = nt * 16 + (lane & 15);
    const int kb = ks * 32 + ((lane >> 4) << 3);
    short8 o;
#pragma unroll
    for (int e = 0; e < 8; ++e) {
        const int k = kb + e;
        float v;
        if (layer == 0) {
            v = (k < 128) ? W1l[k * 128 + col] : W1r[(k - 128) * 128 + col];
        } else {
            if (col < OC) v = (k < 128) ? Wml[k * OC + col] : Wmr[(k - 128) * OC + col];
            else {
                int c2 = col - OC;
                v = (k < 128) ? Wsl[k * OC + c2] : Wsr[(k - 128) * OC + c2];
            }
        }
        o[e] = (short)f2b(v);
    }
    unsigned short* W = (layer == 0) ? Wf1 : Wf2;
    *(short8*)(W + (size_t)f * 8) = o;
}

// ---------------- gather mean-aggregation: one 16-lane slot per node, 8-deep unroll ----------------
__global__ __launch_bounds__(256) void k_agg(const unsigned short* __restrict__ feat,
                                             const int* __restrict__ row_ptr,
                                             const int* __restrict__ csr,
                                             unsigned short* __restrict__ agg) {
    const int lane = threadIdx.x & 63;
    const int wid = threadIdx.x >> 6;
    const int slot = lane >> 4;
    const int cg = lane & 15;
    const int node = blockIdx.x * 16 + wid * 4 + slot;
    if (node >= NN) return;
    const int beg = row_ptr[node];
    const int end = row_ptr[node + 1];
    float acc[8];
#pragma unroll
    for (int q = 0; q < 8; ++q) acc[q] = 0.f;

    for (int j = beg; j < end; j += 8) {
        const int nl = end - j;
        short8 v[8];
#pragma unroll
        for (int u = 0; u < 8; ++u) {
            if (u < nl) {
                int s = csr[j + u];
                v[u] = *(const short8*)(feat + (size_t)s * IC + cg * 8);
            }
        }
#pragma unroll
        for (int u = 0; u < 8; ++u) {
            if (u < nl) {
#pragma unroll
                for (int q = 0; q < 8; ++q) acc[q] += b2f((unsigned short)v[u][q]);
            }
        }
    }
    float inv = 1.0f / fmaxf((float)(end - beg), 1.0f);
    short8 o;
#pragma unroll
    for (int q = 0; q < 8; ++q) o[q] = (short)f2b(acc[q] * inv);
    *(short8*)(agg + (size_t)node * IC + cg * 8) = o;
}

// ---------------- MFMA SAGE GEMM: out = [Agg | X] @ W + b ----------------
// 32 rows/wave, 128 rows/block. A: 16 hoisted gathers pinned in VGPRs.
// B: whole fragment-ordered Wf (64 KB) staged in LDS; conflict-free ds_read_b128.
// MODE 0: bias+relu -> LDS-staged coalesced bf16 stores (h); MODE 1: fp32 mu/logstd.
template <int MODE>
__global__ __launch_bounds__(256) void k_gemm(
    const unsigned short* __restrict__ Agg, const unsigned short* __restrict__ Xb,
    const unsigned short* __restrict__ Wf,
    const float* __restrict__ bias0, const float* __restrict__ bias1,
    unsigned short* __restrict__ hout, float* __restrict__ out_mu,
    float* __restrict__ out_ls) {
    const int lane = threadIdx.x & 63;
    const int wid = threadIdx.x >> 6;
    const int rowg = blockIdx.x * 128 + wid * 32;
    const int r16 = lane & 15;
    const int k8 = (lane >> 4) * 8;

    __shared__ short8 bsm[4096];  // 64 KB: B fragments; reused by MODE0 epilogue

    int rA[2];
#pragma unroll
    for (int m = 0; m < 2; ++m) {
        int r = rowg + m * 16 + r16;
        rA[m] = (r < NN) ? r : (NN - 1);
    }

    // 1) issue all 16 A-fragment gathers
    short8 aF[2][8];
#pragma unroll
    for (int ks = 0; ks < 4; ++ks) {
        aF[0][ks] = *(const short8*)(Agg + (size_t)rA[0] * IC + ks * 32 + k8);
        aF[1][ks] = *(const short8*)(Agg + (size_t)rA[1] * IC + ks * 32 + k8);
    }
#pragma unroll
    for (int ks = 0; ks < 4; ++ks) {
        aF[0][4 + ks] = *(const short8*)(Xb + (size_t)rA[0] * IC + ks * 32 + k8);
        aF[1][4 + ks] = *(const short8*)(Xb + (size_t)rA[1] * IC + ks * 32 + k8);
    }

    // 2) stage B fragments into LDS (overlaps with A gathers in flight)
    const short8* Wg = (const short8*)Wf;
#pragma unroll
    for (int i = 0; i < 16; ++i)
        bsm[i * 256 + threadIdx.x] = Wg[i * 256 + threadIdx.x];

    // 3) pin A fragments in registers (forces the hoist to survive scheduling)
#pragma unroll
    for (int ks = 0; ks < 8; ++ks)
        asm volatile("" :: "v"(aF[0][ks]), "v"(aF[1][ks]));

    __syncthreads();

    f32x4 acc[2][8];
#pragma unroll
    for (int m = 0; m < 2; ++m)
#pragma unroll
        for (int nt = 0; nt < 8; ++nt) acc[m][nt] = (f32x4){0.f, 0.f, 0.f, 0.f};

    // 4) pure LDS + MFMA main loop
#pragma unroll
    for (int ks = 0; ks < 8; ++ks) {
        short8 bF[8];
#pragma unroll
        for (int nt = 0; nt < 8; ++nt) bF[nt] = bsm[(ks * 8 + nt) * 64 + lane];
#pragma unroll
        for (int nt = 0; nt < 8; ++nt) {
            acc[0][nt] = __builtin_amdgcn_mfma_f32_16x16x32_bf16(aF[0][ks], bF[nt], acc[0][nt], 0, 0, 0);
            acc[1][nt] = __builtin_amdgcn_mfma_f32_16x16x32_bf16(aF[1][ks], bF[nt], acc[1][nt], 0, 0, 0);
        }
    }

    const int rbase = (lane >> 4) * 4;
    if (MODE == 0) {
        __syncthreads();  // everyone done reading B before overwrite
        unsigned short* ws = (unsigned short*)bsm + wid * 32 * LDW;
#pragma unroll
        for (int m = 0; m < 2; ++m) {
#pragma unroll
            for (int nt = 0; nt < 8; ++nt) {
                const int c = nt * 16 + r16;
                const float bv = bias0[c];
#pragma unroll
                for (int q = 0; q < 4; ++q) {
                    float v = fmaxf(acc[m][nt][q] + bv, 0.f);
                    ws[(m * 16 + rbase + q) * LDW + c] = f2b(v);
                }
            }
        }
        __syncthreads();
#pragma unroll
        for (int p = 0; p < 8; ++p) {
            const int rloc = p * 4 + (lane >> 4);
            const int row = rowg + rloc;
            if (row < NN) {
                short8 v = *(const short8*)&ws[rloc * LDW + r16 * 8];
                *(short8*)(hout + (size_t)row * IC + r16 * 8) = v;
            }
        }
    } else {
#pragma unroll
        for (int m = 0; m < 2; ++m) {
#pragma unroll
            for (int nt = 0; nt < 8; ++nt) {
                const int c = nt * 16 + r16;
                const float bv = (c < OC) ? bias0[c] : bias1[c - OC];
#pragma unroll
                for (int q = 0; q < 4; ++q) {
                    const int row = rowg + m * 16 + rbase + q;
                    if (row >= NN) continue;
                    float v = acc[m][nt][q] + bv;
                    if (c < OC) out_mu[(size_t)row * OC + c] = v;
                    else        out_ls[(size_t)row * OC + (c - OC)] = v;
                }
            }
        }
    }
}

extern "C" void kernel_launch(void* const* d_in, const int* in_sizes, int n_in,
                              void* d_out, int out_size, void* d_ws, size_t ws_size,
                              hipStream_t stream) {
    const float* x   = (const float*)d_in[0];
    const int*   ei  = (const int*)d_in[1];
    const float* W1l = (const float*)d_in[2];
    const float* W1r = (const float*)d_in[3];
    const float* b1  = (const float*)d_in[4];
    const float* Wml = (const float*)d_in[5];
    const float* Wmr = (const float*)d_in[6];
    const float* bm  = (const float*)d_in[7];
    const float* Wsl = (const float*)d_in[8];
    const float* Wsr = (const float*)d_in[9];
    const float* bs  = (const float*)d_in[10];

    const int* src = ei;
    const int* dst = ei + NE;

    // workspace layout (bytes)
    char* w = (char*)d_ws;
    unsigned short* xb   = (unsigned short*)(w);                 // 25,600,000
    unsigned short* hb   = (unsigned short*)(w + 25600000);      // 25,600,000
    unsigned short* aggb = (unsigned short*)(w + 51200000);      // 25,600,000
    unsigned short* Wf1  = (unsigned short*)(w + 76800000);      // 65,536
    unsigned short* Wf2  = (unsigned short*)(w + 76865536);      // 65,536
    int* row_ptr  = (int*)(w + 76931072);                        // 400,064 (padded)
    int* csr      = (int*)(w + 77331136);                        // 4,000,000
    int* gcur     = (int*)(w + 81331136);                        // 4,096
    int* bstart   = (int*)(w + 81335232);                        // 1,024
    unsigned* bins = (unsigned*)(w + 81336256);                  // 4,718,592

    float* out_mu = (float*)d_out;
    float* out_ls = out_mu + (size_t)NN * OC;

    const int gemm_grid = (NN + 127) / 128;
    const int agg_grid = (NN + 15) / 16;
    const int binA_grid = (NE + EPB - 1) / EPB;

    // ---- CSR build (shared by both layers) ----
    hipMemsetAsync(gcur, 0, NBUCK * GPAD * sizeof(int), stream);
    k_binA<<<binA_grid, 256, 0, stream>>>(src, dst, gcur, bins);
    k_bscan<<<1, 64, 0, stream>>>(gcur, bstart, row_ptr);
    k_binB<<<NBUCK, 512, 0, stream>>>(gcur, bstart, bins, row_ptr, csr);

    // conversions / weight prep
    k_cvt<<<(NN * IC / 8 + 255) / 256, 256, 0, stream>>>(x, xb);
    k_wprep<<<(2 * 4096 + 255) / 256, 256, 0, stream>>>(W1l, W1r, Wml, Wmr, Wsl, Wsr, Wf1, Wf2);

    // layer 1
    k_agg<<<agg_grid, 256, 0, stream>>>(xb, row_ptr, csr, aggb);
    k_gemm<0><<<gemm_grid, 256, 0, stream>>>(aggb, xb, Wf1, b1, nullptr,
                                             hb, nullptr, nullptr);

    // layer 2 (shared aggregation feeds mu and logstd)
    k_agg<<<agg_grid, 256, 0, stream>>>(hb, row_ptr, csr, aggb);
    k_gemm<1><<<gemm_grid, 256, 0, stream>>>(aggb, hb, Wf2, bm, bs,
                                             nullptr, out_mu, out_ls);
}

// Round 10
// 198.502 us; speedup vs baseline: 1.4303x; 1.0095x over previous
//
#include <hip/hip_runtime.h>

#define NN 100000
#define IC 128
#define OC 64
#define NE 1000000

#define NBUCK 64
#define BN 1568         // nodes per bucket; 64*1568 = 100352 >= NN
#define RCAP 18432      // bucket region capacity (mean 15625, +22 sigma)
#define EPB 2048        // edges per binning block
#define CAPA 64         // LDS buffer entries per bucket in k_binA
#define GPAD 16         // gcur padding: one counter per 64B line
#define LDW 136         // epilogue LDS row stride (128 + 8 pad), ushorts
#define CVT_BLOCKS 6250 // NN*IC/8/256

typedef __attribute__((ext_vector_type(8))) short short8;
typedef __attribute__((ext_vector_type(4))) float f32x4;

static __device__ __forceinline__ float b2f(unsigned short u) {
    unsigned v = ((unsigned)u) << 16;
    float f;
    __builtin_memcpy(&f, &v, 4);
    return f;
}
static __device__ __forceinline__ unsigned short f2b(float f) {
    unsigned u;
    __builtin_memcpy(&u, &f, 4);
    u += 0x7fff + ((u >> 16) & 1);
    return (unsigned short)(u >> 16);
}

// ---------------- CSR pass A: partition edges into 64 dst-range buckets ----------------
__global__ __launch_bounds__(256) void k_binA(const int* __restrict__ src,
                                              const int* __restrict__ dst,
                                              int* __restrict__ gcur,
                                              unsigned* __restrict__ bins) {
    __shared__ unsigned buf[NBUCK][CAPA];
    __shared__ int lcnt[NBUCK];
    const int t = threadIdx.x;
    if (t < NBUCK) lcnt[t] = 0;
    __syncthreads();
    const int e0 = blockIdx.x * EPB;
#pragma unroll
    for (int q = 0; q < EPB / 256; ++q) {
        int e = e0 + q * 256 + t;
        if (e < NE) {
            int d = dst[e];
            int s = src[e];
            int b = d / BN;
            unsigned packed = ((unsigned)(d - b * BN) << 17) | (unsigned)s;
            int idx = atomicAdd(&lcnt[b], 1);
            if (idx < CAPA) {
                buf[b][idx] = packed;
            } else {
                int g = atomicAdd(&gcur[b * GPAD], 1);
                if (g < RCAP) bins[(size_t)b * RCAP + g] = packed;
            }
        }
    }
    __syncthreads();
    const int wid = t >> 6, lane = t & 63;
    for (int b = wid * 16; b < wid * 16 + 16; ++b) {
        int c = lcnt[b];
        if (c > CAPA) c = CAPA;
        if (c > 0) {
            int g = 0;
            if (lane == 0) g = atomicAdd(&gcur[b * GPAD], c);
            g = __shfl(g, 0, 64);
            if (lane < c && g + lane < RCAP)
                bins[(size_t)b * RCAP + g + lane] = buf[b][lane];
        }
    }
}

// ---------------- CSR pass B: bucket-scan + per-bucket hist + scan + place ----------------
__global__ __launch_bounds__(512) void k_binB(const int* __restrict__ gcur,
                                              const unsigned* __restrict__ bins,
                                              int* __restrict__ row_ptr,
                                              int* __restrict__ csr) {
    __shared__ int lc[2048];
    __shared__ int rk[2048];
    __shared__ int tsum[512];
    __shared__ int seg[RCAP];
    __shared__ int sh_bs;
    const int b = blockIdx.x;
    const int t = threadIdx.x;
    const int base = b * BN;
    const int nloc = (NN - base < BN) ? (NN - base) : BN;
    // inline exclusive scan over the 64 bucket counts (wave 0)
    if (t < 64) {
        int v = gcur[t * GPAD];
        if (v > RCAP) v = RCAP;
        int s = v;
        for (int off = 1; off < 64; off <<= 1) {
            int u = __shfl_up(s, off, 64);
            if (t >= off) s += u;
        }
        if (t == b) sh_bs = s - v;
        if (b == 0 && t == 63) row_ptr[NN] = s;
    }
    for (int i = t; i < 2048; i += 512) { lc[i] = 0; rk[i] = 0; }
    __syncthreads();
    int c = gcur[b * GPAD];
    if (c > RCAP) c = RCAP;
    const unsigned* mb = bins + (size_t)b * RCAP;
    for (int i = t; i < c; i += 512) atomicAdd(&lc[mb[i] >> 17], 1);
    __syncthreads();
    int loc[4], s = 0;
#pragma unroll
    for (int q = 0; q < 4; ++q) { loc[q] = lc[t * 4 + q]; s += loc[q]; }
    tsum[t] = s;
    __syncthreads();
    for (int off = 1; off < 512; off <<= 1) {
        int u = (t >= off) ? tsum[t - off] : 0;
        __syncthreads();
        tsum[t] += u;
        __syncthreads();
    }
    int run = tsum[t] - s;
#pragma unroll
    for (int q = 0; q < 4; ++q) { lc[t * 4 + q] = run; run += loc[q]; }
    __syncthreads();
    const int bs = sh_bs;
    for (int i = t; i < nloc; i += 512) row_ptr[base + i] = bs + lc[i];
    for (int i = t; i < c; i += 512) {
        unsigned p = mb[i];
        int dl = p >> 17;
        int r = atomicAdd(&rk[dl], 1);
        seg[lc[dl] + r] = (int)(p & 0x1FFFFu);
    }
    __syncthreads();
    for (int i = t; i < c; i += 512) csr[bs + i] = seg[i];
}

// ---------------- fused prep: x fp32->bf16 AND fragment-ordered weights ----------------
__global__ __launch_bounds__(256) void k_prep(
    const float* __restrict__ x, unsigned short* __restrict__ xb,
    const float* __restrict__ W1l, const float* __restrict__ W1r,
    const float* __restrict__ Wml, const float* __restrict__ Wmr,
    const float* __restrict__ Wsl, const float* __restrict__ Wsr,
    unsigned short* __restrict__ Wf1, unsigned short* __restrict__ Wf2) {
    const int blk = blockIdx.x;
    if (blk < CVT_BLOCKS) {
        int t = blk * 256 + threadIdx.x;
        const float4* p = (const float4*)x + (size_t)t * 2;
        float4 f0 = p[0], f1 = p[1];
        short8 o;
        o[0] = (short)f2b(f0.x); o[1] = (short)f2b(f0.y);
        o[2] = (short)f2b(f0.z); o[3] = (short)f2b(f0.w);
        o[4] = (short)f2b(f1.x); o[5] = (short)f2b(f1.y);
        o[6] = (short)f2b(f1.z); o[7] = (short)f2b(f1.w);
        *((short8*)xb + t) = o;
    } else {
        int t = (blk - CVT_BLOCKS) * 256 + threadIdx.x;
        if (t >= 2 * 4096) return;
        const int layer = t >> 12;
        const int f = t & 4095;
        const int lane = f & 63;
        const int nt = (f >> 6) & 7;
        const int ks = f >> 9;
        const int col = nt * 16 + (lane & 15);
        const int kb = ks * 32 + ((lane >> 4) << 3);
        short8 o;
#pragma unroll
        for (int e = 0; e < 8; ++e) {
            const int k = kb + e;
            float v;
            if (layer == 0) {
                v = (k < 128) ? W1l[k * 128 + col] : W1r[(k - 128) * 128 + col];
            } else {
                if (col < OC) v = (k < 128) ? Wml[k * OC + col] : Wmr[(k - 128) * OC + col];
                else {
                    int c2 = col - OC;
                    v = (k < 128) ? Wsl[k * OC + c2] : Wsr[(k - 128) * OC + c2];
                }
            }
            o[e] = (short)f2b(v);
        }
        unsigned short* W = (layer == 0) ? Wf1 : Wf2;
        *(short8*)(W + (size_t)f * 8) = o;
    }
}

// ---------------- gather mean-aggregation: one 16-lane slot per node, 8-deep unroll ----------------
__global__ __launch_bounds__(256) void k_agg(const unsigned short* __restrict__ feat,
                                             const int* __restrict__ row_ptr,
                                             const int* __restrict__ csr,
                                             unsigned short* __restrict__ agg) {
    const int lane = threadIdx.x & 63;
    const int wid = threadIdx.x >> 6;
    const int slot = lane >> 4;
    const int cg = lane & 15;
    const int node = blockIdx.x * 16 + wid * 4 + slot;
    if (node >= NN) return;
    const int beg = row_ptr[node];
    const int end = row_ptr[node + 1];
    float acc[8];
#pragma unroll
    for (int q = 0; q < 8; ++q) acc[q] = 0.f;

    for (int j = beg; j < end; j += 8) {
        const int nl = end - j;
        short8 v[8];
#pragma unroll
        for (int u = 0; u < 8; ++u) {
            if (u < nl) {
                int s = csr[j + u];
                v[u] = *(const short8*)(feat + (size_t)s * IC + cg * 8);
            }
        }
#pragma unroll
        for (int u = 0; u < 8; ++u) {
            if (u < nl) {
#pragma unroll
                for (int q = 0; q < 8; ++q) acc[q] += b2f((unsigned short)v[u][q]);
            }
        }
    }
    float inv = 1.0f / fmaxf((float)(end - beg), 1.0f);
    short8 o;
#pragma unroll
    for (int q = 0; q < 8; ++q) o[q] = (short)f2b(acc[q] * inv);
    *(short8*)(agg + (size_t)node * IC + cg * 8) = o;
}

// ---------------- MFMA SAGE GEMM: out = [Agg | X] @ W + b ----------------
// 32 rows/wave, 128 rows/block. A: 16 hoisted gathers pinned in VGPRs.
// B: fragment-ordered Wf staged in TWO 32KB K-halves (LDS ~34KB -> 3-4 blocks/CU).
// MODE 0: bias+relu -> LDS-staged coalesced bf16 stores (h); MODE 1: fp32 mu/logstd.
template <int MODE>
__global__ __launch_bounds__(256) void k_gemm(
    const unsigned short* __restrict__ Agg, const unsigned short* __restrict__ Xb,
    const unsigned short* __restrict__ Wf,
    const float* __restrict__ bias0, const float* __restrict__ bias1,
    unsigned short* __restrict__ hout, float* __restrict__ out_mu,
    float* __restrict__ out_ls) {
    const int lane = threadIdx.x & 63;
    const int wid = threadIdx.x >> 6;
    const int rowg = blockIdx.x * 128 + wid * 32;
    const int r16 = lane & 15;
    const int k8 = (lane >> 4) * 8;

    // MODE0: 4*32*LDW ushorts = 34816 B (>= 32768 B B-half); MODE1: 32768 B
    __shared__ unsigned short smem[MODE == 0 ? (4 * 32 * LDW) : 16384];
    short8* bsm = (short8*)smem;

    int rA[2];
#pragma unroll
    for (int m = 0; m < 2; ++m) {
        int r = rowg + m * 16 + r16;
        rA[m] = (r < NN) ? r : (NN - 1);
    }

    // 1) issue all 16 A-fragment gathers
    short8 aF[2][8];
#pragma unroll
    for (int ks = 0; ks < 4; ++ks) {
        aF[0][ks] = *(const short8*)(Agg + (size_t)rA[0] * IC + ks * 32 + k8);
        aF[1][ks] = *(const short8*)(Agg + (size_t)rA[1] * IC + ks * 32 + k8);
    }
#pragma unroll
    for (int ks = 0; ks < 4; ++ks) {
        aF[0][4 + ks] = *(const short8*)(Xb + (size_t)rA[0] * IC + ks * 32 + k8);
        aF[1][4 + ks] = *(const short8*)(Xb + (size_t)rA[1] * IC + ks * 32 + k8);
    }

    // 2) stage B K-half 0 (fragments 0..2047, ks 0..3)
    const short8* Wg = (const short8*)Wf;
#pragma unroll
    for (int i = 0; i < 8; ++i)
        bsm[i * 256 + threadIdx.x] = Wg[i * 256 + threadIdx.x];

    // 3) pin A fragments in registers
#pragma unroll
    for (int ks = 0; ks < 8; ++ks)
        asm volatile("" :: "v"(aF[0][ks]), "v"(aF[1][ks]));

    __syncthreads();

    f32x4 acc[2][8];
#pragma unroll
    for (int m = 0; m < 2; ++m)
#pragma unroll
        for (int nt = 0; nt < 8; ++nt) acc[m][nt] = (f32x4){0.f, 0.f, 0.f, 0.f};

    // 4) phase 0: ks 0..3
#pragma unroll
    for (int ks = 0; ks < 4; ++ks) {
        short8 bF[8];
#pragma unroll
        for (int nt = 0; nt < 8; ++nt) bF[nt] = bsm[(ks * 8 + nt) * 64 + lane];
#pragma unroll
        for (int nt = 0; nt < 8; ++nt) {
            acc[0][nt] = __builtin_amdgcn_mfma_f32_16x16x32_bf16(aF[0][ks], bF[nt], acc[0][nt], 0, 0, 0);
            acc[1][nt] = __builtin_amdgcn_mfma_f32_16x16x32_bf16(aF[1][ks], bF[nt], acc[1][nt], 0, 0, 0);
        }
    }
    __syncthreads();
    // 5) stage B K-half 1 (fragments 2048..4095, ks 4..7)
#pragma unroll
    for (int i = 0; i < 8; ++i)
        bsm[i * 256 + threadIdx.x] = Wg[2048 + i * 256 + threadIdx.x];
    __syncthreads();
#pragma unroll
    for (int ks = 4; ks < 8; ++ks) {
        short8 bF[8];
#pragma unroll
        for (int nt = 0; nt < 8; ++nt) bF[nt] = bsm[((ks - 4) * 8 + nt) * 64 + lane];
#pragma unroll
        for (int nt = 0; nt < 8; ++nt) {
            acc[0][nt] = __builtin_amdgcn_mfma_f32_16x16x32_bf16(aF[0][ks], bF[nt], acc[0][nt], 0, 0, 0);
            acc[1][nt] = __builtin_amdgcn_mfma_f32_16x16x32_bf16(aF[1][ks], bF[nt], acc[1][nt], 0, 0, 0);
        }
    }

    const int rbase = (lane >> 4) * 4;
    if (MODE == 0) {
        __syncthreads();  // everyone done reading B before overwrite
        unsigned short* ws = smem + wid * 32 * LDW;
#pragma unroll
        for (int m = 0; m < 2; ++m) {
#pragma unroll
            for (int nt = 0; nt < 8; ++nt) {
                const int c = nt * 16 + r16;
                const float bv = bias0[c];
#pragma unroll
                for (int q = 0; q < 4; ++q) {
                    float v = fmaxf(acc[m][nt][q] + bv, 0.f);
                    ws[(m * 16 + rbase + q) * LDW + c] = f2b(v);
                }
            }
        }
        __syncthreads();
#pragma unroll
        for (int p = 0; p < 8; ++p) {
            const int rloc = p * 4 + (lane >> 4);
            const int row = rowg + rloc;
            if (row < NN) {
                short8 v = *(const short8*)&ws[rloc * LDW + r16 * 8];
                *(short8*)(hout + (size_t)row * IC + r16 * 8) = v;
            }
        }
    } else {
#pragma unroll
        for (int m = 0; m < 2; ++m) {
#pragma unroll
            for (int nt = 0; nt < 8; ++nt) {
                const int c = nt * 16 + r16;
                const float bv = (c < OC) ? bias0[c] : bias1[c - OC];
#pragma unroll
                for (int q = 0; q < 4; ++q) {
                    const int row = rowg + m * 16 + rbase + q;
                    if (row >= NN) continue;
                    float v = acc[m][nt][q] + bv;
                    if (c < OC) out_mu[(size_t)row * OC + c] = v;
                    else        out_ls[(size_t)row * OC + (c - OC)] = v;
                }
            }
        }
    }
}

extern "C" void kernel_launch(void* const* d_in, const int* in_sizes, int n_in,
                              void* d_out, int out_size, void* d_ws, size_t ws_size,
                              hipStream_t stream) {
    const float* x   = (const float*)d_in[0];
    const int*   ei  = (const int*)d_in[1];
    const float* W1l = (const float*)d_in[2];
    const float* W1r = (const float*)d_in[3];
    const float* b1  = (const float*)d_in[4];
    const float* Wml = (const float*)d_in[5];
    const float* Wmr = (const float*)d_in[6];
    const float* bm  = (const float*)d_in[7];
    const float* Wsl = (const float*)d_in[8];
    const float* Wsr = (const float*)d_in[9];
    const float* bs  = (const float*)d_in[10];

    const int* src = ei;
    const int* dst = ei + NE;

    // workspace layout (bytes)
    char* w = (char*)d_ws;
    unsigned short* xb   = (unsigned short*)(w);                 // 25,600,000
    unsigned short* hb   = (unsigned short*)(w + 25600000);      // 25,600,000
    unsigned short* aggb = (unsigned short*)(w + 51200000);      // 25,600,000
    unsigned short* Wf1  = (unsigned short*)(w + 76800000);      // 65,536
    unsigned short* Wf2  = (unsigned short*)(w + 76865536);      // 65,536
    int* row_ptr  = (int*)(w + 76931072);                        // 400,064 (padded)
    int* csr      = (int*)(w + 77331136);                        // 4,000,000
    int* gcur     = (int*)(w + 81331136);                        // 4,096
    unsigned* bins = (unsigned*)(w + 81336256);                  // 4,718,592

    float* out_mu = (float*)d_out;
    float* out_ls = out_mu + (size_t)NN * OC;

    const int gemm_grid = (NN + 127) / 128;
    const int agg_grid = (NN + 15) / 16;
    const int binA_grid = (NE + EPB - 1) / EPB;

    // ---- CSR build (shared by both layers) ----
    hipMemsetAsync(gcur, 0, NBUCK * GPAD * sizeof(int), stream);
    k_binA<<<binA_grid, 256, 0, stream>>>(src, dst, gcur, bins);
    k_binB<<<NBUCK, 512, 0, stream>>>(gcur, bins, row_ptr, csr);

    // fused conversions / weight prep
    k_prep<<<CVT_BLOCKS + 32, 256, 0, stream>>>(x, xb, W1l, W1r, Wml, Wmr, Wsl, Wsr, Wf1, Wf2);

    // layer 1
    k_agg<<<agg_grid, 256, 0, stream>>>(xb, row_ptr, csr, aggb);
    k_gemm<0><<<gemm_grid, 256, 0, stream>>>(aggb, xb, Wf1, b1, nullptr,
                                             hb, nullptr, nullptr);

    // layer 2 (shared aggregation feeds mu and logstd)
    k_agg<<<agg_grid, 256, 0, stream>>>(hb, row_ptr, csr, aggb);
    k_gemm<1><<<gemm_grid, 256, 0, stream>>>(aggb, hb, Wf2, bm, bs,
                                             nullptr, out_mu, out_ls);
}

// Round 11
// 174.057 us; speedup vs baseline: 1.6312x; 1.1404x over previous
//
#include <hip/hip_runtime.h>

#define NN 100000
#define IC 128
#define OC 64
#define NE 1000000

#define NBUCK 256
#define BN 392          // nodes per bucket; 256*392 = 100352 >= NN
#define RCAP 4608       // bucket region capacity (mean 3906, +11 sigma)
#define EPB 2048        // edges per binning block
#define CAPA 24         // LDS buffer entries per bucket per block (mean 8, P(>24)~1e-6)
#define GPAD 16         // gcur padding: one counter per 64B line
#define LDW 136         // epilogue LDS row stride (128 + 8 pad), ushorts
#define BINA_GRID 489   // ceil(NE/EPB)
#define CVT_BLOCKS 6250 // NN*IC/8/256

typedef __attribute__((ext_vector_type(8))) short short8;
typedef __attribute__((ext_vector_type(4))) float f32x4;

static __device__ __forceinline__ float b2f(unsigned short u) {
    unsigned v = ((unsigned)u) << 16;
    float f;
    __builtin_memcpy(&f, &v, 4);
    return f;
}
static __device__ __forceinline__ unsigned short f2b(float f) {
    unsigned u;
    __builtin_memcpy(&u, &f, 4);
    u += 0x7fff + ((u >> 16) & 1);
    return (unsigned short)(u >> 16);
}

// ---------------- fp8 e4m3 encode/decode (hw cvt if available, manual fallback) ----------------
#if defined(__has_builtin)
#if __has_builtin(__builtin_amdgcn_cvt_pk_fp8_f32) && __has_builtin(__builtin_amdgcn_cvt_pk_f32_fp8)
#define HW_FP8 1
#endif
#endif

static __device__ __forceinline__ unsigned f2q1(float f) {  // manual e4m3fn, FTZ
    unsigned u;
    __builtin_memcpy(&u, &f, 4);
    unsigned s = (u >> 24) & 0x80u;
    unsigned a = u & 0x7FFFFFFFu;
    if (a < 0x3C000000u) return s;          // |f| < 2^-7 -> 0
    if (a < 0x3C800000u) return s | 0x08u;  // [2^-7, 2^-6) -> min normal
    if (a >= 0x43E00000u) return s | 0x7Eu; // >= 448 clamp
    a += 0x7FFFFu + ((a >> 20) & 1u);       // RNE to 3 mantissa bits
    unsigned e = (a >> 23) - 120u;
    unsigned m = (a >> 20) & 7u;
    unsigned c = (e << 3) | m;
    if (c > 0x7Eu) c = 0x7Eu;
    return s | c;
}
static __device__ __forceinline__ float q1f(unsigned q) {
    unsigned em = q & 0x7Fu;
    unsigned s = (q & 0x80u) << 24;
    unsigned u = (em >= 8u) ? (s | (((em >> 3) + 120u) << 23) | ((em & 7u) << 20)) : s;
    float f;
    __builtin_memcpy(&f, &u, 4);
    return f;
}

static __device__ __forceinline__ unsigned pack4_fp8(float a, float b, float c, float d) {
#ifdef HW_FP8
    int r = __builtin_amdgcn_cvt_pk_fp8_f32(a, b, 0, false);
    r = __builtin_amdgcn_cvt_pk_fp8_f32(c, d, r, true);
    return (unsigned)r;
#else
    return f2q1(a) | (f2q1(b) << 8) | (f2q1(c) << 16) | (f2q1(d) << 24);
#endif
}

// ---------------- CSR pass A body: partition edges into 256 dst-range buckets ----------------
__device__ __forceinline__ void binA_body(int blk, int t,
                                          const int* __restrict__ src,
                                          const int* __restrict__ dst,
                                          int* __restrict__ gcur,
                                          unsigned* __restrict__ bins,
                                          unsigned (*buf)[CAPA], int* lcnt, int* goff) {
    lcnt[t] = 0;
    __syncthreads();
    const int e0 = blk * EPB;
#pragma unroll
    for (int q = 0; q < EPB / 256; ++q) {
        int e = e0 + q * 256 + t;
        if (e < NE) {
            int d = dst[e];
            int s = src[e];
            int b = d / BN;
            unsigned packed = ((unsigned)(d - b * BN) << 17) | (unsigned)s;
            int idx = atomicAdd(&lcnt[b], 1);
            if (idx < CAPA) {
                buf[b][idx] = packed;
            } else {  // overflow slow path (p ~ 1e-6 per bucket-block)
                int g = atomicAdd(&gcur[b * GPAD], 1);
                if (g < RCAP) bins[(size_t)b * RCAP + g] = packed;
            }
        }
    }
    __syncthreads();
    // phase 1: 256 parallel cursor atomics (one per bucket, lanes in parallel)
    int c = lcnt[t];
    if (c > CAPA) c = CAPA;
    if (c > 0) goff[t] = atomicAdd(&gcur[t * GPAD], c);
    __syncthreads();
    // phase 2: fire-and-forget coalesced flush, wave wid -> buckets [wid*64, wid*64+64)
    const int wid = t >> 6, lane = t & 63;
    for (int b = wid * 64; b < wid * 64 + 64; ++b) {
        int cb = lcnt[b];
        if (cb > CAPA) cb = CAPA;
        if (lane < cb) {
            int g = goff[b] + lane;
            if (g < RCAP) bins[(size_t)b * RCAP + g] = buf[b][lane];
        }
    }
}

// ---------------- fused front kernel: binA | x->bf16+fp8 | weight prep ----------------
__global__ __launch_bounds__(256) void k_front(
    const int* __restrict__ src, const int* __restrict__ dst,
    int* __restrict__ gcur, unsigned* __restrict__ bins,
    const float* __restrict__ x, unsigned short* __restrict__ xb,
    unsigned char* __restrict__ xq,
    const float* __restrict__ W1l, const float* __restrict__ W1r,
    const float* __restrict__ Wml, const float* __restrict__ Wmr,
    const float* __restrict__ Wsl, const float* __restrict__ Wsr,
    unsigned short* __restrict__ Wf1, unsigned short* __restrict__ Wf2) {
    __shared__ unsigned buf[NBUCK][CAPA];  // 24.6 KB
    __shared__ int lcnt[NBUCK];
    __shared__ int goff[NBUCK];
    const int blk = blockIdx.x;
    const int tid = threadIdx.x;
    if (blk < BINA_GRID) {
        binA_body(blk, tid, src, dst, gcur, bins, buf, lcnt, goff);
    } else if (blk < BINA_GRID + CVT_BLOCKS) {
        int t = (blk - BINA_GRID) * 256 + tid;
        const float4* p = (const float4*)x + (size_t)t * 2;
        float4 f0 = p[0], f1 = p[1];
        short8 o;
        o[0] = (short)f2b(f0.x); o[1] = (short)f2b(f0.y);
        o[2] = (short)f2b(f0.z); o[3] = (short)f2b(f0.w);
        o[4] = (short)f2b(f1.x); o[5] = (short)f2b(f1.y);
        o[6] = (short)f2b(f1.z); o[7] = (short)f2b(f1.w);
        *((short8*)xb + t) = o;
        uint2 q;
        q.x = pack4_fp8(f0.x, f0.y, f0.z, f0.w);
        q.y = pack4_fp8(f1.x, f1.y, f1.z, f1.w);
        *((uint2*)xq + t) = q;
    } else {
        int t = (blk - BINA_GRID - CVT_BLOCKS) * 256 + tid;
        if (t >= 2 * 4096) return;
        const int layer = t >> 12;
        const int f = t & 4095;
        const int lane = f & 63;
        const int nt = (f >> 6) & 7;
        const int ks = f >> 9;
        const int col = nt * 16 + (lane & 15);
        const int kb = ks * 32 + ((lane >> 4) << 3);
        short8 o;
#pragma unroll
        for (int e = 0; e < 8; ++e) {
            const int k = kb + e;
            float v;
            if (layer == 0) {
                v = (k < 128) ? W1l[k * 128 + col] : W1r[(k - 128) * 128 + col];
            } else {
                if (col < OC) v = (k < 128) ? Wml[k * OC + col] : Wmr[(k - 128) * OC + col];
                else {
                    int c2 = col - OC;
                    v = (k < 128) ? Wsl[k * OC + c2] : Wsr[(k - 128) * OC + c2];
                }
            }
            o[e] = (short)f2b(v);
        }
        unsigned short* W = (layer == 0) ? Wf1 : Wf2;
        *(short8*)(W + (size_t)f * 8) = o;
    }
}

// ---------------- CSR pass B: bucket-scan + per-bucket hist + scan + place ----------------
__global__ __launch_bounds__(256) void k_binB(const int* __restrict__ gcur,
                                              const unsigned* __restrict__ bins,
                                              int* __restrict__ row_ptr,
                                              int* __restrict__ csr) {
    __shared__ int lc[512];
    __shared__ int rk[512];
    __shared__ int tsum[256];
    __shared__ int seg[RCAP];  // 18.4 KB
    __shared__ int sh_bs;
    const int b = blockIdx.x;
    const int t = threadIdx.x;
    const int base = b * BN;
    const int nloc = (NN - base < BN) ? (NN - base) : BN;
    // inline exclusive scan over all 256 bucket counts
    int v = gcur[t * GPAD];
    if (v > RCAP) v = RCAP;
    tsum[t] = v;
    __syncthreads();
    for (int off = 1; off < 256; off <<= 1) {
        int u = (t >= off) ? tsum[t - off] : 0;
        __syncthreads();
        tsum[t] += u;
        __syncthreads();
    }
    if (t == b) sh_bs = tsum[t] - v;
    if (b == 0 && t == 255) row_ptr[NN] = tsum[255];
    lc[t] = 0; lc[t + 256] = 0;
    rk[t] = 0; rk[t + 256] = 0;
    __syncthreads();
    int c = gcur[b * GPAD];
    if (c > RCAP) c = RCAP;
    const unsigned* mb = bins + (size_t)b * RCAP;
    for (int i = t; i < c; i += 256) atomicAdd(&lc[mb[i] >> 17], 1);
    __syncthreads();
    int l0 = lc[2 * t], l1 = lc[2 * t + 1];
    int s = l0 + l1;
    tsum[t] = s;
    __syncthreads();
    for (int off = 1; off < 256; off <<= 1) {
        int u = (t >= off) ? tsum[t - off] : 0;
        __syncthreads();
        tsum[t] += u;
        __syncthreads();
    }
    int run = tsum[t] - s;
    lc[2 * t] = run;
    lc[2 * t + 1] = run + l0;
    __syncthreads();
    const int bs = sh_bs;
    for (int i = t; i < nloc; i += 256) row_ptr[base + i] = bs + lc[i];
    for (int i = t; i < c; i += 256) {
        unsigned p = mb[i];
        int dl = p >> 17;
        int r = atomicAdd(&rk[dl], 1);
        seg[lc[dl] + r] = (int)(p & 0x1FFFFu);
    }
    __syncthreads();
    for (int i = t; i < c; i += 256) csr[bs + i] = seg[i];
}

// ---------------- gather mean-aggregation: one 16-lane slot per node, 8-deep unroll ----------------
// FP8=1: featq fp8 rows (8 B/lane); FP8=0: feat bf16 rows (16 B/lane). f32 accum, bf16 out.
template <int FP8>
__global__ __launch_bounds__(256) void k_agg(const unsigned short* __restrict__ feat,
                                             const unsigned char* __restrict__ featq,
                                             const int* __restrict__ row_ptr,
                                             const int* __restrict__ csr,
                                             unsigned short* __restrict__ agg) {
    const int lane = threadIdx.x & 63;
    const int wid = threadIdx.x >> 6;
    const int slot = lane >> 4;
    const int cg = lane & 15;
    const int node = blockIdx.x * 16 + wid * 4 + slot;
    if (node >= NN) return;
    const int beg = row_ptr[node];
    const int end = row_ptr[node + 1];
    float acc[8];
#pragma unroll
    for (int q = 0; q < 8; ++q) acc[q] = 0.f;

    if (FP8) {
        for (int j = beg; j < end; j += 8) {
            const int nl = end - j;
            uint2 v[8];
#pragma unroll
            for (int u = 0; u < 8; ++u) {
                if (u < nl) {
                    int s = csr[j + u];
                    v[u] = *(const uint2*)(featq + (size_t)s * IC + cg * 8);
                }
            }
#pragma unroll
            for (int u = 0; u < 8; ++u) {
                if (u < nl) {
#ifdef HW_FP8
                    auto p0 = __builtin_amdgcn_cvt_pk_f32_fp8((int)v[u].x, false);
                    auto p1 = __builtin_amdgcn_cvt_pk_f32_fp8((int)v[u].x, true);
                    auto p2 = __builtin_amdgcn_cvt_pk_f32_fp8((int)v[u].y, false);
                    auto p3 = __builtin_amdgcn_cvt_pk_f32_fp8((int)v[u].y, true);
                    acc[0] += p0[0]; acc[1] += p0[1];
                    acc[2] += p1[0]; acc[3] += p1[1];
                    acc[4] += p2[0]; acc[5] += p2[1];
                    acc[6] += p3[0]; acc[7] += p3[1];
#else
#pragma unroll
                    for (int q = 0; q < 4; ++q) acc[q] += q1f((v[u].x >> (8 * q)) & 0xFFu);
#pragma unroll
                    for (int q = 0; q < 4; ++q) acc[4 + q] += q1f((v[u].y >> (8 * q)) & 0xFFu);
#endif
                }
            }
        }
    } else {
        for (int j = beg; j < end; j += 8) {
            const int nl = end - j;
            short8 v[8];
#pragma unroll
            for (int u = 0; u < 8; ++u) {
                if (u < nl) {
                    int s = csr[j + u];
                    v[u] = *(const short8*)(feat + (size_t)s * IC + cg * 8);
                }
            }
#pragma unroll
            for (int u = 0; u < 8; ++u) {
                if (u < nl) {
#pragma unroll
                    for (int q = 0; q < 8; ++q) acc[q] += b2f((unsigned short)v[u][q]);
                }
            }
        }
    }
    float inv = 1.0f / fmaxf((float)(end - beg), 1.0f);
    short8 o;
#pragma unroll
    for (int q = 0; q < 8; ++q) o[q] = (short)f2b(acc[q] * inv);
    *(short8*)(agg + (size_t)node * IC + cg * 8) = o;
}

// ---------------- MFMA SAGE GEMM: out = [Agg | X] @ W + b ----------------
// 32 rows/wave, 128 rows/block. A: 16 hoisted gathers pinned in VGPRs.
// B: fragment-ordered Wf staged in TWO 32KB K-halves (LDS ~34KB -> 3-4 blocks/CU).
// MODE 0: bias+relu -> LDS-staged coalesced bf16 stores (h); MODE 1: fp32 mu/logstd.
template <int MODE>
__global__ __launch_bounds__(256) void k_gemm(
    const unsigned short* __restrict__ Agg, const unsigned short* __restrict__ Xb,
    const unsigned short* __restrict__ Wf,
    const float* __restrict__ bias0, const float* __restrict__ bias1,
    unsigned short* __restrict__ hout, float* __restrict__ out_mu,
    float* __restrict__ out_ls) {
    const int lane = threadIdx.x & 63;
    const int wid = threadIdx.x >> 6;
    const int rowg = blockIdx.x * 128 + wid * 32;
    const int r16 = lane & 15;
    const int k8 = (lane >> 4) * 8;

    __shared__ unsigned short smem[MODE == 0 ? (4 * 32 * LDW) : 16384];
    short8* bsm = (short8*)smem;

    int rA[2];
#pragma unroll
    for (int m = 0; m < 2; ++m) {
        int r = rowg + m * 16 + r16;
        rA[m] = (r < NN) ? r : (NN - 1);
    }

    short8 aF[2][8];
#pragma unroll
    for (int ks = 0; ks < 4; ++ks) {
        aF[0][ks] = *(const short8*)(Agg + (size_t)rA[0] * IC + ks * 32 + k8);
        aF[1][ks] = *(const short8*)(Agg + (size_t)rA[1] * IC + ks * 32 + k8);
    }
#pragma unroll
    for (int ks = 0; ks < 4; ++ks) {
        aF[0][4 + ks] = *(const short8*)(Xb + (size_t)rA[0] * IC + ks * 32 + k8);
        aF[1][4 + ks] = *(const short8*)(Xb + (size_t)rA[1] * IC + ks * 32 + k8);
    }

    const short8* Wg = (const short8*)Wf;
#pragma unroll
    for (int i = 0; i < 8; ++i)
        bsm[i * 256 + threadIdx.x] = Wg[i * 256 + threadIdx.x];

#pragma unroll
    for (int ks = 0; ks < 8; ++ks)
        asm volatile("" :: "v"(aF[0][ks]), "v"(aF[1][ks]));

    __syncthreads();

    f32x4 acc[2][8];
#pragma unroll
    for (int m = 0; m < 2; ++m)
#pragma unroll
        for (int nt = 0; nt < 8; ++nt) acc[m][nt] = (f32x4){0.f, 0.f, 0.f, 0.f};

#pragma unroll
    for (int ks = 0; ks < 4; ++ks) {
        short8 bF[8];
#pragma unroll
        for (int nt = 0; nt < 8; ++nt) bF[nt] = bsm[(ks * 8 + nt) * 64 + lane];
#pragma unroll
        for (int nt = 0; nt < 8; ++nt) {
            acc[0][nt] = __builtin_amdgcn_mfma_f32_16x16x32_bf16(aF[0][ks], bF[nt], acc[0][nt], 0, 0, 0);
            acc[1][nt] = __builtin_amdgcn_mfma_f32_16x16x32_bf16(aF[1][ks], bF[nt], acc[1][nt], 0, 0, 0);
        }
    }
    __syncthreads();
#pragma unroll
    for (int i = 0; i < 8; ++i)
        bsm[i * 256 + threadIdx.x] = Wg[2048 + i * 256 + threadIdx.x];
    __syncthreads();
#pragma unroll
    for (int ks = 4; ks < 8; ++ks) {
        short8 bF[8];
#pragma unroll
        for (int nt = 0; nt < 8; ++nt) bF[nt] = bsm[((ks - 4) * 8 + nt) * 64 + lane];
#pragma unroll
        for (int nt = 0; nt < 8; ++nt) {
            acc[0][nt] = __builtin_amdgcn_mfma_f32_16x16x32_bf16(aF[0][ks], bF[nt], acc[0][nt], 0, 0, 0);
            acc[1][nt] = __builtin_amdgcn_mfma_f32_16x16x32_bf16(aF[1][ks], bF[nt], acc[1][nt], 0, 0, 0);
        }
    }

    const int rbase = (lane >> 4) * 4;
    if (MODE == 0) {
        __syncthreads();
        unsigned short* ws = smem + wid * 32 * LDW;
#pragma unroll
        for (int m = 0; m < 2; ++m) {
#pragma unroll
            for (int nt = 0; nt < 8; ++nt) {
                const int c = nt * 16 + r16;
                const float bv = bias0[c];
#pragma unroll
                for (int q = 0; q < 4; ++q) {
                    float v = fmaxf(acc[m][nt][q] + bv, 0.f);
                    ws[(m * 16 + rbase + q) * LDW + c] = f2b(v);
                }
            }
        }
        __syncthreads();
#pragma unroll
        for (int p = 0; p < 8; ++p) {
            const int rloc = p * 4 + (lane >> 4);
            const int row = rowg + rloc;
            if (row < NN) {
                short8 v = *(const short8*)&ws[rloc * LDW + r16 * 8];
                *(short8*)(hout + (size_t)row * IC + r16 * 8) = v;
            }
        }
    } else {
#pragma unroll
        for (int m = 0; m < 2; ++m) {
#pragma unroll
            for (int nt = 0; nt < 8; ++nt) {
                const int c = nt * 16 + r16;
                const float bv = (c < OC) ? bias0[c] : bias1[c - OC];
#pragma unroll
                for (int q = 0; q < 4; ++q) {
                    const int row = rowg + m * 16 + rbase + q;
                    if (row >= NN) continue;
                    float v = acc[m][nt][q] + bv;
                    if (c < OC) out_mu[(size_t)row * OC + c] = v;
                    else        out_ls[(size_t)row * OC + (c - OC)] = v;
                }
            }
        }
    }
}

extern "C" void kernel_launch(void* const* d_in, const int* in_sizes, int n_in,
                              void* d_out, int out_size, void* d_ws, size_t ws_size,
                              hipStream_t stream) {
    const float* x   = (const float*)d_in[0];
    const int*   ei  = (const int*)d_in[1];
    const float* W1l = (const float*)d_in[2];
    const float* W1r = (const float*)d_in[3];
    const float* b1  = (const float*)d_in[4];
    const float* Wml = (const float*)d_in[5];
    const float* Wmr = (const float*)d_in[6];
    const float* bm  = (const float*)d_in[7];
    const float* Wsl = (const float*)d_in[8];
    const float* Wsr = (const float*)d_in[9];
    const float* bs  = (const float*)d_in[10];

    const int* src = ei;
    const int* dst = ei + NE;

    // workspace layout (bytes)
    char* w = (char*)d_ws;
    unsigned short* xb   = (unsigned short*)(w);                 // 25,600,000
    unsigned short* hb   = (unsigned short*)(w + 25600000);      // 25,600,000
    unsigned short* aggb = (unsigned short*)(w + 51200000);      // 25,600,000
    unsigned short* Wf1  = (unsigned short*)(w + 76800000);      // 65,536
    unsigned short* Wf2  = (unsigned short*)(w + 76865536);      // 65,536
    int* row_ptr  = (int*)(w + 76931072);                        // 400,128 (padded)
    int* csr      = (int*)(w + 77331200);                        // 4,000,000
    int* gcur     = (int*)(w + 81331200);                        // 16,384
    unsigned* bins = (unsigned*)(w + 81347584);                  // 4,718,592
    unsigned char* xq = (unsigned char*)(w + 86066176);          // 12,800,000 -> end ~98.9 MB

    float* out_mu = (float*)d_out;
    float* out_ls = out_mu + (size_t)NN * OC;

    const int gemm_grid = (NN + 127) / 128;
    const int agg_grid = (NN + 15) / 16;

    // ---- CSR build + conversions (fused front) ----
    hipMemsetAsync(gcur, 0, NBUCK * GPAD * sizeof(int), stream);
    k_front<<<BINA_GRID + CVT_BLOCKS + 32, 256, 0, stream>>>(
        src, dst, gcur, bins, x, xb, xq, W1l, W1r, Wml, Wmr, Wsl, Wsr, Wf1, Wf2);
    k_binB<<<NBUCK, 256, 0, stream>>>(gcur, bins, row_ptr, csr);

    // layer 1 (fp8 gather)
    k_agg<1><<<agg_grid, 256, 0, stream>>>(nullptr, xq, row_ptr, csr, aggb);
    k_gemm<0><<<gemm_grid, 256, 0, stream>>>(aggb, xb, Wf1, b1, nullptr,
                                             hb, nullptr, nullptr);

    // layer 2 (bf16 gather; shared aggregation feeds mu and logstd)
    k_agg<0><<<agg_grid, 256, 0, stream>>>(hb, nullptr, row_ptr, csr, aggb);
    k_gemm<1><<<gemm_grid, 256, 0, stream>>>(aggb, hb, Wf2, bm, bs,
                                             nullptr, out_mu, out_ls);
}

// Round 12
// 170.291 us; speedup vs baseline: 1.6673x; 1.0221x over previous
//
#include <hip/hip_runtime.h>

#define NN 100000
#define IC 128
#define OC 64
#define NE 1000000

#define NBUCK 256
#define BN 392          // nodes per bucket; 256*392 = 100352 >= NN
#define RCAP 4608       // bucket region capacity (mean 3906, +11 sigma)
#define EPB 2048        // edges per binning block
#define CAPA 24         // LDS buffer entries per bucket per block
#define GPAD 16         // gcur padding: one counter per 64B line
#define LDW 136         // epilogue LDS row stride (128 + 8 pad), ushorts
#define BINA_GRID 489   // ceil(NE/EPB)
#define CVT_BLOCKS 6250 // NN*IC/8/256

typedef __attribute__((ext_vector_type(8))) short short8;
typedef __attribute__((ext_vector_type(4))) float f32x4;

static __device__ __forceinline__ float b2f(unsigned short u) {
    unsigned v = ((unsigned)u) << 16;
    float f;
    __builtin_memcpy(&f, &v, 4);
    return f;
}
static __device__ __forceinline__ unsigned short f2b(float f) {
    unsigned u;
    __builtin_memcpy(&u, &f, 4);
    u += 0x7fff + ((u >> 16) & 1);
    return (unsigned short)(u >> 16);
}

// ---------------- fp8 e4m3 encode/decode (hw cvt if available, manual fallback) ----------------
#if defined(__has_builtin)
#if __has_builtin(__builtin_amdgcn_cvt_pk_fp8_f32) && __has_builtin(__builtin_amdgcn_cvt_pk_f32_fp8)
#define HW_FP8 1
#endif
#endif

static __device__ __forceinline__ unsigned f2q1(float f) {  // manual e4m3fn, FTZ
    unsigned u;
    __builtin_memcpy(&u, &f, 4);
    unsigned s = (u >> 24) & 0x80u;
    unsigned a = u & 0x7FFFFFFFu;
    if (a < 0x3C000000u) return s;
    if (a < 0x3C800000u) return s | 0x08u;
    if (a >= 0x43E00000u) return s | 0x7Eu;
    a += 0x7FFFFu + ((a >> 20) & 1u);
    unsigned e = (a >> 23) - 120u;
    unsigned m = (a >> 20) & 7u;
    unsigned c = (e << 3) | m;
    if (c > 0x7Eu) c = 0x7Eu;
    return s | c;
}
static __device__ __forceinline__ float q1f(unsigned q) {
    unsigned em = q & 0x7Fu;
    unsigned s = (q & 0x80u) << 24;
    unsigned u = (em >= 8u) ? (s | (((em >> 3) + 120u) << 23) | ((em & 7u) << 20)) : s;
    float f;
    __builtin_memcpy(&f, &u, 4);
    return f;
}

static __device__ __forceinline__ unsigned pack4_fp8(float a, float b, float c, float d) {
#ifdef HW_FP8
    int r = __builtin_amdgcn_cvt_pk_fp8_f32(a, b, 0, false);
    r = __builtin_amdgcn_cvt_pk_fp8_f32(c, d, r, true);
    return (unsigned)r;
#else
    return f2q1(a) | (f2q1(b) << 8) | (f2q1(c) << 16) | (f2q1(d) << 24);
#endif
}
static __device__ __forceinline__ void dec4(unsigned w, float* o) {
#ifdef HW_FP8
    auto p0 = __builtin_amdgcn_cvt_pk_f32_fp8((int)w, false);
    auto p1 = __builtin_amdgcn_cvt_pk_f32_fp8((int)w, true);
    o[0] = p0[0]; o[1] = p0[1]; o[2] = p1[0]; o[3] = p1[1];
#else
#pragma unroll
    for (int q = 0; q < 4; ++q) o[q] = q1f((w >> (8 * q)) & 0xFFu);
#endif
}

// ---------------- CSR pass A body: partition edges into 256 dst-range buckets ----------------
__device__ __forceinline__ void binA_body(int blk, int t,
                                          const int* __restrict__ src,
                                          const int* __restrict__ dst,
                                          int* __restrict__ gcur,
                                          unsigned* __restrict__ bins,
                                          unsigned (*buf)[CAPA], int* lcnt, int* goff) {
    lcnt[t] = 0;
    __syncthreads();
    const int e0 = blk * EPB;
#pragma unroll
    for (int q = 0; q < EPB / 256; ++q) {
        int e = e0 + q * 256 + t;
        if (e < NE) {
            int d = dst[e];
            int s = src[e];
            int b = d / BN;
            unsigned packed = ((unsigned)(d - b * BN) << 17) | (unsigned)s;
            int idx = atomicAdd(&lcnt[b], 1);
            if (idx < CAPA) {
                buf[b][idx] = packed;
            } else {
                int g = atomicAdd(&gcur[b * GPAD], 1);
                if (g < RCAP) bins[(size_t)b * RCAP + g] = packed;
            }
        }
    }
    __syncthreads();
    int c = lcnt[t];
    if (c > CAPA) c = CAPA;
    if (c > 0) goff[t] = atomicAdd(&gcur[t * GPAD], c);
    __syncthreads();
    const int wid = t >> 6, lane = t & 63;
    for (int b = wid * 64; b < wid * 64 + 64; ++b) {
        int cb = lcnt[b];
        if (cb > CAPA) cb = CAPA;
        if (lane < cb) {
            int g = goff[b] + lane;
            if (g < RCAP) bins[(size_t)b * RCAP + g] = buf[b][lane];
        }
    }
}

// ---------------- fused front kernel: binA | x->bf16+fp8 | weight prep ----------------
__global__ __launch_bounds__(256) void k_front(
    const int* __restrict__ src, const int* __restrict__ dst,
    int* __restrict__ gcur, unsigned* __restrict__ bins,
    const float* __restrict__ x, unsigned short* __restrict__ xb,
    unsigned char* __restrict__ xq,
    const float* __restrict__ W1l, const float* __restrict__ W1r,
    const float* __restrict__ Wml, const float* __restrict__ Wmr,
    const float* __restrict__ Wsl, const float* __restrict__ Wsr,
    unsigned short* __restrict__ Wf1, unsigned short* __restrict__ Wf2) {
    __shared__ unsigned buf[NBUCK][CAPA];
    __shared__ int lcnt[NBUCK];
    __shared__ int goff[NBUCK];
    const int blk = blockIdx.x;
    const int tid = threadIdx.x;
    if (blk < BINA_GRID) {
        binA_body(blk, tid, src, dst, gcur, bins, buf, lcnt, goff);
    } else if (blk < BINA_GRID + CVT_BLOCKS) {
        int t = (blk - BINA_GRID) * 256 + tid;
        const float4* p = (const float4*)x + (size_t)t * 2;
        float4 f0 = p[0], f1 = p[1];
        short8 o;
        o[0] = (short)f2b(f0.x); o[1] = (short)f2b(f0.y);
        o[2] = (short)f2b(f0.z); o[3] = (short)f2b(f0.w);
        o[4] = (short)f2b(f1.x); o[5] = (short)f2b(f1.y);
        o[6] = (short)f2b(f1.z); o[7] = (short)f2b(f1.w);
        *((short8*)xb + t) = o;
        uint2 q;
        q.x = pack4_fp8(f0.x, f0.y, f0.z, f0.w);
        q.y = pack4_fp8(f1.x, f1.y, f1.z, f1.w);
        *((uint2*)xq + t) = q;
    } else {
        int t = (blk - BINA_GRID - CVT_BLOCKS) * 256 + tid;
        if (t >= 2 * 4096) return;
        const int layer = t >> 12;
        const int f = t & 4095;
        const int lane = f & 63;
        const int nt = (f >> 6) & 7;
        const int ks = f >> 9;
        const int col = nt * 16 + (lane & 15);
        const int kb = ks * 32 + ((lane >> 4) << 3);
        short8 o;
#pragma unroll
        for (int e = 0; e < 8; ++e) {
            const int k = kb + e;
            float v;
            if (layer == 0) {
                v = (k < 128) ? W1l[k * 128 + col] : W1r[(k - 128) * 128 + col];
            } else {
                if (col < OC) v = (k < 128) ? Wml[k * OC + col] : Wmr[(k - 128) * OC + col];
                else {
                    int c2 = col - OC;
                    v = (k < 128) ? Wsl[k * OC + c2] : Wsr[(k - 128) * OC + c2];
                }
            }
            o[e] = (short)f2b(v);
        }
        unsigned short* W = (layer == 0) ? Wf1 : Wf2;
        *(short8*)(W + (size_t)f * 8) = o;
    }
}

// ---------------- CSR pass B: scan + hist + place + degree-sorted order ----------------
__global__ __launch_bounds__(256) void k_binB(const int* __restrict__ gcur,
                                              const unsigned* __restrict__ bins,
                                              int* __restrict__ row_ptr,
                                              int* __restrict__ csr,
                                              int* __restrict__ order) {
    __shared__ int lc[512];
    __shared__ int rk[512];
    __shared__ int tsum[256];
    __shared__ int dh[64];
    __shared__ int seg[RCAP];
    __shared__ int sh_bs;
    const int b = blockIdx.x;
    const int t = threadIdx.x;
    const int base = b * BN;
    const int nloc = (NN - base < BN) ? (NN - base) : BN;
    // exclusive scan over all 256 bucket counts
    int v = gcur[t * GPAD];
    if (v > RCAP) v = RCAP;
    tsum[t] = v;
    __syncthreads();
    for (int off = 1; off < 256; off <<= 1) {
        int u = (t >= off) ? tsum[t - off] : 0;
        __syncthreads();
        tsum[t] += u;
        __syncthreads();
    }
    if (t == b) sh_bs = tsum[t] - v;
    if (b == 0 && t == 255) row_ptr[NN] = tsum[255];
    lc[t] = 0; lc[t + 256] = 0;
    rk[t] = 0; rk[t + 256] = 0;
    if (t < 64) dh[t] = 0;
    __syncthreads();
    int c = gcur[b * GPAD];
    if (c > RCAP) c = RCAP;
    const unsigned* mb = bins + (size_t)b * RCAP;
    for (int i = t; i < c; i += 256) atomicAdd(&lc[mb[i] >> 17], 1);
    __syncthreads();
    int l0 = lc[2 * t], l1 = lc[2 * t + 1];
    // degree histogram (for wave-balance sort)
    const int d0 = (l0 < 64) ? l0 : 63;
    const int d1 = (l1 < 64) ? l1 : 63;
    if (2 * t < nloc) atomicAdd(&dh[d0], 1);
    if (2 * t + 1 < nloc) atomicAdd(&dh[d1], 1);
    int s = l0 + l1;
    tsum[t] = s;
    __syncthreads();
    for (int off = 1; off < 256; off <<= 1) {
        int u = (t >= off) ? tsum[t - off] : 0;
        __syncthreads();
        tsum[t] += u;
        __syncthreads();
    }
    int run = tsum[t] - s;
    lc[2 * t] = run;
    lc[2 * t + 1] = run + l0;
    // exclusive scan of degree histogram (wave 0; hist complete since tsum scan synced)
    if (t < 64) {
        int dv = dh[t];
        int sc = dv;
        for (int off = 1; off < 64; off <<= 1) {
            int u = __shfl_up(sc, off, 64);
            if (t >= off) sc += u;
        }
        dh[t] = sc - dv;  // becomes per-degree cursor
    }
    __syncthreads();
    // degree-sorted node order (within bucket)
    if (2 * t < nloc) { int p = atomicAdd(&dh[d0], 1); order[base + p] = base + 2 * t; }
    if (2 * t + 1 < nloc) { int p = atomicAdd(&dh[d1], 1); order[base + p] = base + 2 * t + 1; }
    const int bs = sh_bs;
    for (int i = t; i < nloc; i += 256) row_ptr[base + i] = bs + lc[i];
    for (int i = t; i < c; i += 256) {
        unsigned p = mb[i];
        int dl = p >> 17;
        int r = atomicAdd(&rk[dl], 1);
        seg[lc[dl] + r] = (int)(p & 0x1FFFFu);
    }
    __syncthreads();
    for (int i = t; i < c; i += 256) csr[bs + i] = seg[i];
}

// ---------------- gather mean-aggregation (degree-sorted order) ----------------
// FP8=1: 8-lane slots, 16B/lane (full 128B fp8 row), 8 nodes/wave.
// FP8=0: 16-lane slots, 16B/lane (256B bf16 row), 4 nodes/wave.
template <int FP8>
__global__ __launch_bounds__(256) void k_agg(const unsigned short* __restrict__ feat,
                                             const unsigned char* __restrict__ featq,
                                             const int* __restrict__ row_ptr,
                                             const int* __restrict__ csr,
                                             const int* __restrict__ order,
                                             unsigned short* __restrict__ agg) {
    const int lane = threadIdx.x & 63;
    const int wid = threadIdx.x >> 6;
    if (FP8) {
        const int slot = lane >> 3;
        const int cl = lane & 7;
        const int idx = blockIdx.x * 32 + wid * 8 + slot;
        if (idx >= NN) return;
        const int node = order[idx];
        const int beg = row_ptr[node];
        const int end = row_ptr[node + 1];
        float acc[16];
#pragma unroll
        for (int q = 0; q < 16; ++q) acc[q] = 0.f;
        for (int j = beg; j < end; j += 8) {
            const int nl = end - j;
            uint4 v[8];
#pragma unroll
            for (int u = 0; u < 8; ++u) {
                if (u < nl) {
                    int s = csr[j + u];
                    v[u] = *(const uint4*)(featq + (size_t)s * IC + cl * 16);
                }
            }
#pragma unroll
            for (int u = 0; u < 8; ++u) {
                if (u < nl) {
                    float d[16];
                    dec4(v[u].x, d); dec4(v[u].y, d + 4);
                    dec4(v[u].z, d + 8); dec4(v[u].w, d + 12);
#pragma unroll
                    for (int q = 0; q < 16; ++q) acc[q] += d[q];
                }
            }
        }
        float inv = 1.0f / fmaxf((float)(end - beg), 1.0f);
        short8 o0, o1;
#pragma unroll
        for (int q = 0; q < 8; ++q) o0[q] = (short)f2b(acc[q] * inv);
#pragma unroll
        for (int q = 0; q < 8; ++q) o1[q] = (short)f2b(acc[8 + q] * inv);
        *(short8*)(agg + (size_t)node * IC + cl * 16) = o0;
        *(short8*)(agg + (size_t)node * IC + cl * 16 + 8) = o1;
    } else {
        const int slot = lane >> 4;
        const int cg = lane & 15;
        const int idx = blockIdx.x * 16 + wid * 4 + slot;
        if (idx >= NN) return;
        const int node = order[idx];
        const int beg = row_ptr[node];
        const int end = row_ptr[node + 1];
        float acc[8];
#pragma unroll
        for (int q = 0; q < 8; ++q) acc[q] = 0.f;
        for (int j = beg; j < end; j += 8) {
            const int nl = end - j;
            short8 v[8];
#pragma unroll
            for (int u = 0; u < 8; ++u) {
                if (u < nl) {
                    int s = csr[j + u];
                    v[u] = *(const short8*)(feat + (size_t)s * IC + cg * 8);
                }
            }
#pragma unroll
            for (int u = 0; u < 8; ++u) {
                if (u < nl) {
#pragma unroll
                    for (int q = 0; q < 8; ++q) acc[q] += b2f((unsigned short)v[u][q]);
                }
            }
        }
        float inv = 1.0f / fmaxf((float)(end - beg), 1.0f);
        short8 o;
#pragma unroll
        for (int q = 0; q < 8; ++q) o[q] = (short)f2b(acc[q] * inv);
        *(short8*)(agg + (size_t)node * IC + cg * 8) = o;
    }
}

// ---------------- MFMA SAGE GEMM: out = [Agg | X] @ W + b ----------------
template <int MODE>
__global__ __launch_bounds__(256) void k_gemm(
    const unsigned short* __restrict__ Agg, const unsigned short* __restrict__ Xb,
    const unsigned short* __restrict__ Wf,
    const float* __restrict__ bias0, const float* __restrict__ bias1,
    unsigned short* __restrict__ hout, float* __restrict__ out_mu,
    float* __restrict__ out_ls) {
    const int lane = threadIdx.x & 63;
    const int wid = threadIdx.x >> 6;
    const int rowg = blockIdx.x * 128 + wid * 32;
    const int r16 = lane & 15;
    const int k8 = (lane >> 4) * 8;

    __shared__ unsigned short smem[MODE == 0 ? (4 * 32 * LDW) : 16384];
    short8* bsm = (short8*)smem;

    int rA[2];
#pragma unroll
    for (int m = 0; m < 2; ++m) {
        int r = rowg + m * 16 + r16;
        rA[m] = (r < NN) ? r : (NN - 1);
    }

    short8 aF[2][8];
#pragma unroll
    for (int ks = 0; ks < 4; ++ks) {
        aF[0][ks] = *(const short8*)(Agg + (size_t)rA[0] * IC + ks * 32 + k8);
        aF[1][ks] = *(const short8*)(Agg + (size_t)rA[1] * IC + ks * 32 + k8);
    }
#pragma unroll
    for (int ks = 0; ks < 4; ++ks) {
        aF[0][4 + ks] = *(const short8*)(Xb + (size_t)rA[0] * IC + ks * 32 + k8);
        aF[1][4 + ks] = *(const short8*)(Xb + (size_t)rA[1] * IC + ks * 32 + k8);
    }

    const short8* Wg = (const short8*)Wf;
#pragma unroll
    for (int i = 0; i < 8; ++i)
        bsm[i * 256 + threadIdx.x] = Wg[i * 256 + threadIdx.x];

#pragma unroll
    for (int ks = 0; ks < 8; ++ks)
        asm volatile("" :: "v"(aF[0][ks]), "v"(aF[1][ks]));

    __syncthreads();

    f32x4 acc[2][8];
#pragma unroll
    for (int m = 0; m < 2; ++m)
#pragma unroll
        for (int nt = 0; nt < 8; ++nt) acc[m][nt] = (f32x4){0.f, 0.f, 0.f, 0.f};

#pragma unroll
    for (int ks = 0; ks < 4; ++ks) {
        short8 bF[8];
#pragma unroll
        for (int nt = 0; nt < 8; ++nt) bF[nt] = bsm[(ks * 8 + nt) * 64 + lane];
#pragma unroll
        for (int nt = 0; nt < 8; ++nt) {
            acc[0][nt] = __builtin_amdgcn_mfma_f32_16x16x32_bf16(aF[0][ks], bF[nt], acc[0][nt], 0, 0, 0);
            acc[1][nt] = __builtin_amdgcn_mfma_f32_16x16x32_bf16(aF[1][ks], bF[nt], acc[1][nt], 0, 0, 0);
        }
    }
    __syncthreads();
#pragma unroll
    for (int i = 0; i < 8; ++i)
        bsm[i * 256 + threadIdx.x] = Wg[2048 + i * 256 + threadIdx.x];
    __syncthreads();
#pragma unroll
    for (int ks = 4; ks < 8; ++ks) {
        short8 bF[8];
#pragma unroll
        for (int nt = 0; nt < 8; ++nt) bF[nt] = bsm[((ks - 4) * 8 + nt) * 64 + lane];
#pragma unroll
        for (int nt = 0; nt < 8; ++nt) {
            acc[0][nt] = __builtin_amdgcn_mfma_f32_16x16x32_bf16(aF[0][ks], bF[nt], acc[0][nt], 0, 0, 0);
            acc[1][nt] = __builtin_amdgcn_mfma_f32_16x16x32_bf16(aF[1][ks], bF[nt], acc[1][nt], 0, 0, 0);
        }
    }

    const int rbase = (lane >> 4) * 4;
    if (MODE == 0) {
        __syncthreads();
        unsigned short* ws = smem + wid * 32 * LDW;
#pragma unroll
        for (int m = 0; m < 2; ++m) {
#pragma unroll
            for (int nt = 0; nt < 8; ++nt) {
                const int c = nt * 16 + r16;
                const float bv = bias0[c];
#pragma unroll
                for (int q = 0; q < 4; ++q) {
                    float v = fmaxf(acc[m][nt][q] + bv, 0.f);
                    ws[(m * 16 + rbase + q) * LDW + c] = f2b(v);
                }
            }
        }
        __syncthreads();
#pragma unroll
        for (int p = 0; p < 8; ++p) {
            const int rloc = p * 4 + (lane >> 4);
            const int row = rowg + rloc;
            if (row < NN) {
                short8 v = *(const short8*)&ws[rloc * LDW + r16 * 8];
                *(short8*)(hout + (size_t)row * IC + r16 * 8) = v;
            }
        }
    } else {
#pragma unroll
        for (int m = 0; m < 2; ++m) {
#pragma unroll
            for (int nt = 0; nt < 8; ++nt) {
                const int c = nt * 16 + r16;
                const float bv = (c < OC) ? bias0[c] : bias1[c - OC];
#pragma unroll
                for (int q = 0; q < 4; ++q) {
                    const int row = rowg + m * 16 + rbase + q;
                    if (row >= NN) continue;
                    float v = acc[m][nt][q] + bv;
                    if (c < OC) out_mu[(size_t)row * OC + c] = v;
                    else        out_ls[(size_t)row * OC + (c - OC)] = v;
                }
            }
        }
    }
}

extern "C" void kernel_launch(void* const* d_in, const int* in_sizes, int n_in,
                              void* d_out, int out_size, void* d_ws, size_t ws_size,
                              hipStream_t stream) {
    const float* x   = (const float*)d_in[0];
    const int*   ei  = (const int*)d_in[1];
    const float* W1l = (const float*)d_in[2];
    const float* W1r = (const float*)d_in[3];
    const float* b1  = (const float*)d_in[4];
    const float* Wml = (const float*)d_in[5];
    const float* Wmr = (const float*)d_in[6];
    const float* bm  = (const float*)d_in[7];
    const float* Wsl = (const float*)d_in[8];
    const float* Wsr = (const float*)d_in[9];
    const float* bs  = (const float*)d_in[10];

    const int* src = ei;
    const int* dst = ei + NE;

    // workspace layout (bytes)
    char* w = (char*)d_ws;
    unsigned short* xb   = (unsigned short*)(w);                 // 25,600,000
    unsigned short* hb   = (unsigned short*)(w + 25600000);      // 25,600,000
    unsigned short* aggb = (unsigned short*)(w + 51200000);      // 25,600,000
    unsigned short* Wf1  = (unsigned short*)(w + 76800000);      // 65,536
    unsigned short* Wf2  = (unsigned short*)(w + 76865536);      // 65,536
    int* row_ptr  = (int*)(w + 76931072);                        // 400,128 (padded)
    int* csr      = (int*)(w + 77331200);                        // 4,000,000
    int* gcur     = (int*)(w + 81331200);                        // 16,384
    unsigned* bins = (unsigned*)(w + 81347584);                  // 4,718,592
    unsigned char* xq = (unsigned char*)(w + 86066176);          // 12,800,000
    int* order    = (int*)(w + 98866176);                        // 400,000 -> end ~99.3 MB

    float* out_mu = (float*)d_out;
    float* out_ls = out_mu + (size_t)NN * OC;

    const int gemm_grid = (NN + 127) / 128;
    const int agg1_grid = (NN + 31) / 32;
    const int agg2_grid = (NN + 15) / 16;

    // ---- CSR build + conversions (fused front) ----
    hipMemsetAsync(gcur, 0, NBUCK * GPAD * sizeof(int), stream);
    k_front<<<BINA_GRID + CVT_BLOCKS + 32, 256, 0, stream>>>(
        src, dst, gcur, bins, x, xb, xq, W1l, W1r, Wml, Wmr, Wsl, Wsr, Wf1, Wf2);
    k_binB<<<NBUCK, 256, 0, stream>>>(gcur, bins, row_ptr, csr, order);

    // layer 1 (fp8 gather, 8-lane slots)
    k_agg<1><<<agg1_grid, 256, 0, stream>>>(nullptr, xq, row_ptr, csr, order, aggb);
    k_gemm<0><<<gemm_grid, 256, 0, stream>>>(aggb, xb, Wf1, b1, nullptr,
                                             hb, nullptr, nullptr);

    // layer 2 (bf16 gather; shared aggregation feeds mu and logstd)
    k_agg<0><<<agg2_grid, 256, 0, stream>>>(hb, nullptr, row_ptr, csr, order, aggb);
    k_gemm<1><<<gemm_grid, 256, 0, stream>>>(aggb, hb, Wf2, bm, bs,
                                             nullptr, out_mu, out_ls);
}